// Round 1
// baseline (982.518 us; speedup 1.0000x reference)
//
#include <hip/hip_runtime.h>
#include <hip/hip_bf16.h>
#include <stdint.h>

#define NE 25690112ull   // 32*64*112*112
#define PP 12544         // 112*112
#define SS 112
#define EPSV 1e-5f

__device__ __forceinline__ unsigned short f2bf(float x){
  union { float f; uint32_t u; } v; v.f = x;
  uint32_t r = (v.u + 0x7fffu + ((v.u >> 16) & 1u)) >> 16;
  return (unsigned short)r;
}
__device__ __forceinline__ float bflo(uint32_t u){ return __uint_as_float(u << 16); }
__device__ __forceinline__ float bfhi(uint32_t u){ return __uint_as_float(u & 0xffff0000u); }

// K1: conv1x1 GEMM. out[b,o,p] = sum_c W[o,c]*X[b,c,p] + bias[o], bf16 outputs.
// z=0: X=rgb -> (qF,kF) with wq_fad/wk_fad; z=1: X=fre -> (qL,kL) with wq_lfs/wk_lfs
__global__ __launch_bounds__(256) void k1_conv(
    const float* __restrict__ rgb, const float* __restrict__ fre,
    const float* __restrict__ wq_fad, const float* __restrict__ bq_fad,
    const float* __restrict__ wk_fad, const float* __restrict__ bk_fad,
    const float* __restrict__ wq_lfs, const float* __restrict__ bq_lfs,
    const float* __restrict__ wk_lfs, const float* __restrict__ bk_lfs,
    unsigned short* __restrict__ qF, unsigned short* __restrict__ kF,
    unsigned short* __restrict__ qL, unsigned short* __restrict__ kL)
{
  const int pt = blockIdx.x, b = blockIdx.y, z = blockIdx.z;
  const float* X  = z ? fre : rgb;
  const float* Wq = z ? wq_lfs : wq_fad;
  const float* Bq = z ? bq_lfs : bq_fad;
  const float* Wk = z ? wk_lfs : wk_fad;
  const float* Bk = z ? bk_lfs : bk_fad;
  unsigned short* Oq = z ? qL : qF;
  unsigned short* Ok = z ? kL : kF;

  __shared__ float Xs[64][128];
  __shared__ float Wqs[64][64];   // transposed: Wqs[c][o]
  __shared__ float Wks[64][64];
  const int tid = threadIdx.x;
  for (int i = tid; i < 4096; i += 256){
    int o = i >> 6, c = i & 63;
    Wqs[c][o] = Wq[i];
    Wks[c][o] = Wk[i];
  }
  const int p0 = pt * 128;
  const size_t baseX = ((size_t)b * 64) * PP + p0;
  for (int i = tid; i < 8192; i += 256){
    int c = i >> 7, p = i & 127;
    Xs[c][p] = X[baseX + (size_t)c * PP + p];
  }
  __syncthreads();
  const int tx = tid & 31, oy = tid >> 5;
  float accq[8][4], acck[8][4];
  #pragma unroll
  for (int o = 0; o < 8; ++o){
    float bq = Bq[oy*8+o], bk = Bk[oy*8+o];
    #pragma unroll
    for (int p = 0; p < 4; ++p){ accq[o][p] = bq; acck[o][p] = bk; }
  }
  #pragma unroll 4
  for (int c = 0; c < 64; ++c){
    const float4 xv = *(const float4*)(&Xs[c][tx*4]);
    const float4 a0 = *(const float4*)(&Wqs[c][oy*8]);
    const float4 a1 = *(const float4*)(&Wqs[c][oy*8+4]);
    const float4 b0 = *(const float4*)(&Wks[c][oy*8]);
    const float4 b1 = *(const float4*)(&Wks[c][oy*8+4]);
    float xx[4] = {xv.x, xv.y, xv.z, xv.w};
    float wq[8] = {a0.x,a0.y,a0.z,a0.w,a1.x,a1.y,a1.z,a1.w};
    float wk[8] = {b0.x,b0.y,b0.z,b0.w,b1.x,b1.y,b1.z,b1.w};
    #pragma unroll
    for (int o = 0; o < 8; ++o)
      #pragma unroll
      for (int p = 0; p < 4; ++p){
        accq[o][p] = fmaf(wq[o], xx[p], accq[o][p]);
        acck[o][p] = fmaf(wk[o], xx[p], acck[o][p]);
      }
  }
  #pragma unroll
  for (int o = 0; o < 8; ++o){
    size_t off = ((size_t)b*64 + oy*8+o) * PP + p0 + tx*4;
    ushort4 sq, sk;
    sq.x = f2bf(accq[o][0]); sq.y = f2bf(accq[o][1]); sq.z = f2bf(accq[o][2]); sq.w = f2bf(accq[o][3]);
    sk.x = f2bf(acck[o][0]); sk.y = f2bf(acck[o][1]); sk.z = f2bf(acck[o][2]); sk.w = f2bf(acck[o][3]);
    *(ushort4*)(&Oq[off]) = sq;
    *(ushort4*)(&Ok[off]) = sk;
  }
}

// K2: fused attention per (b,c): logits = qF.kF^T + qL.kL^T, softmax rows,
// t1 = fre*attn*sL (att_lfs), t2 = rgb*attn*sF (att_fad); accumulate per-channel
// sum/sumsq of t1,t2 into stats[0..255].
__global__ __launch_bounds__(256) void k2_attn(
    const unsigned short* __restrict__ qF, const unsigned short* __restrict__ qL,
    const unsigned short* __restrict__ kF, const unsigned short* __restrict__ kL,
    const float* __restrict__ rgb, const float* __restrict__ fre,
    const float* __restrict__ fad_gamma, const float* __restrict__ lfs_gamma,
    float* __restrict__ t1, float* __restrict__ t2, float* __restrict__ stats)
{
  const int bc = blockIdx.x;
  const int c = bc & 63;
  const size_t plane = (size_t)bc * PP;
  __shared__ uint32_t ksF[112][57];   // packed bf16 pairs, pitch 57 (conflict-free)
  __shared__ uint32_t ksL[112][57];
  __shared__ float qsF[16][112];
  __shared__ float qsL[16][112];
  const int tid = threadIdx.x;
  const int lane = tid & 63, wave = tid >> 6;

  const uint32_t* kFu = (const uint32_t*)(kF) + plane/2;
  const uint32_t* kLu = (const uint32_t*)(kL) + plane/2;
  for (int i = tid; i < 6272; i += 256){
    int j = i / 56, w2 = i % 56;
    ksF[j][w2] = kFu[i];
    ksL[j][w2] = kLu[i];
  }
  const float sF = 2.f/(1.f + __expf(-fad_gamma[0])) - 1.f;
  const float sL = 2.f/(1.f + __expf(-lfs_gamma[0])) - 1.f;
  const uint32_t* qFu = (const uint32_t*)(qF) + plane/2;
  const uint32_t* qLu = (const uint32_t*)(qL) + plane/2;
  const int j1 = lane;
  const bool has2 = lane < 48;
  const int j2 = has2 ? lane + 64 : 0;
  float ls1 = 0.f, lq1 = 0.f, ls2 = 0.f, lq2 = 0.f;

  for (int it = 0; it < 7; ++it){
    __syncthreads();
    for (int i = tid; i < 896; i += 256){
      int r = i / 56, w2 = i % 56;
      uint32_t ua = qFu[(it*16 + r)*56 + w2];
      uint32_t ub = qLu[(it*16 + r)*56 + w2];
      qsF[r][2*w2]   = bflo(ua); qsF[r][2*w2+1] = bfhi(ua);
      qsL[r][2*w2]   = bflo(ub); qsL[r][2*w2+1] = bfhi(ub);
    }
    __syncthreads();
    float accL0[4] = {0.f,0.f,0.f,0.f};
    float accL1[4] = {0.f,0.f,0.f,0.f};
    const int wr0 = wave*4;
    for (int wc = 0; wc < 28; ++wc){
      const int w2 = wc*2;
      uint32_t uF1a = ksF[j1][w2], uF1b = ksF[j1][w2+1];
      uint32_t uL1a = ksL[j1][w2], uL1b = ksL[j1][w2+1];
      uint32_t uF2a = ksF[j2][w2], uF2b = ksF[j2][w2+1];
      uint32_t uL2a = ksL[j2][w2], uL2b = ksL[j2][w2+1];
      float f10 = bflo(uF1a), f11 = bfhi(uF1a), f12 = bflo(uF1b), f13 = bfhi(uF1b);
      float g10 = bflo(uL1a), g11 = bfhi(uL1a), g12 = bflo(uL1b), g13 = bfhi(uL1b);
      float f20 = bflo(uF2a), f21 = bfhi(uF2a), f22 = bflo(uF2b), f23 = bfhi(uF2b);
      float g20 = bflo(uL2a), g21 = bfhi(uL2a), g22 = bflo(uL2b), g23 = bfhi(uL2b);
      #pragma unroll
      for (int r = 0; r < 4; ++r){
        const float4 qf = *(const float4*)(&qsF[wr0+r][wc*4]);
        const float4 ql = *(const float4*)(&qsL[wr0+r][wc*4]);
        accL0[r] += qf.x*f10 + qf.y*f11 + qf.z*f12 + qf.w*f13
                  + ql.x*g10 + ql.y*g11 + ql.z*g12 + ql.w*g13;
        accL1[r] += qf.x*f20 + qf.y*f21 + qf.z*f22 + qf.w*f23
                  + ql.x*g20 + ql.y*g21 + ql.z*g22 + ql.w*g23;
      }
    }
    #pragma unroll
    for (int r = 0; r < 4; ++r){
      const int i = it*16 + wr0 + r;
      float l0 = accL0[r];
      float l1 = has2 ? accL1[r] : -3.0e38f;
      float m = fmaxf(l0, l1);
      #pragma unroll
      for (int off = 32; off; off >>= 1) m = fmaxf(m, __shfl_xor(m, off, 64));
      float e0 = __expf(l0 - m);
      float e1 = has2 ? __expf(l1 - m) : 0.f;
      float s = e0 + e1;
      #pragma unroll
      for (int off = 32; off; off >>= 1) s += __shfl_xor(s, off, 64);
      float inv = 1.f / s;
      float a0 = e0 * inv, a1 = e1 * inv;
      size_t rb = plane + (size_t)i * SS;
      float fr0 = fre[rb + j1], rg0 = rgb[rb + j1];
      float v1 = fr0 * a0 * sL, v2 = rg0 * a0 * sF;
      t1[rb + j1] = v1; t2[rb + j1] = v2;
      ls1 += v1; lq1 += v1*v1; ls2 += v2; lq2 += v2*v2;
      if (has2){
        float fr1 = fre[rb + j2], rg1 = rgb[rb + j2];
        float u1 = fr1 * a1 * sL, u2 = rg1 * a1 * sF;
        t1[rb + j2] = u1; t2[rb + j2] = u2;
        ls1 += u1; lq1 += u1*u1; ls2 += u2; lq2 += u2*u2;
      }
    }
  }
  #pragma unroll
  for (int off = 32; off; off >>= 1){
    ls1 += __shfl_xor(ls1, off, 64);
    lq1 += __shfl_xor(lq1, off, 64);
    ls2 += __shfl_xor(ls2, off, 64);
    lq2 += __shfl_xor(lq2, off, 64);
  }
  if (lane == 0){
    atomicAdd(&stats[c],       ls1);
    atomicAdd(&stats[64 + c],  lq1);
    atomicAdd(&stats[128 + c], ls2);
    atomicAdd(&stats[192 + c], lq2);
  }
}

// K3: fold bn1 stats into per-channel affine A,B.  y = x_in + A*t + B
__global__ void k3_affine1(const float* __restrict__ stats,
    const float* __restrict__ fad_cw, const float* __restrict__ fad_cb,
    const float* __restrict__ fad_bg, const float* __restrict__ fad_bb,
    const float* __restrict__ lfs_cw, const float* __restrict__ lfs_cb,
    const float* __restrict__ lfs_bg, const float* __restrict__ lfs_bb,
    float* __restrict__ AB)
{
  int c = threadIdx.x;
  if (c >= 64) return;
  const float n = 401408.f;
  {
    float m1 = stats[c]/n, v1 = stats[64+c]/n - (stats[c]/n)*(stats[c]/n);
    float cw = fad_cw[c], g = fad_bg[c];
    float rs = rsqrtf(cw*cw*v1 + EPSV);
    AB[c]      = cw*rs*g;
    AB[64 + c] = -cw*m1*rs*g + fad_bb[c];
    (void)fad_cb;
  }
  {
    float m2 = stats[128+c]/n, v2 = stats[192+c]/n - (stats[128+c]/n)*(stats[128+c]/n);
    float cw = lfs_cw[c], g = lfs_bg[c];
    float rs = rsqrtf(cw*cw*v2 + EPSV);
    AB[128 + c] = cw*rs*g;
    AB[192 + c] = -cw*m2*rs*g + lfs_bb[c];
    (void)lfs_cb;
  }
}

// K4: y_fad = rgb + A1*t1 + B1 (in place over t1); y_lfs = fre + A2*t2 + B2
__global__ __launch_bounds__(256) void k4_y(
    const float* __restrict__ rgb, const float* __restrict__ fre,
    float* __restrict__ t1, float* __restrict__ t2,
    const float* __restrict__ AB)
{
  const int c = blockIdx.x, b = blockIdx.y, z = blockIdx.z;
  const size_t plane = ((size_t)b*64 + c) * PP;
  const float* xin = z ? fre : rgb;
  float* t = z ? t2 : t1;
  const float A = AB[z*128 + c], Bv = AB[z*128 + 64 + c];
  for (int p4 = threadIdx.x; p4 < 3136; p4 += 256){
    float4 xv = *(const float4*)(&xin[plane + (size_t)p4*4]);
    float4 tv = *(const float4*)(&t[plane + (size_t)p4*4]);
    float4 y;
    y.x = xv.x + A*tv.x + Bv;
    y.y = xv.y + A*tv.y + Bv;
    y.z = xv.z + A*tv.z + Bv;
    y.w = xv.w + A*tv.w + Bv;
    *(float4*)(&t[plane + (size_t)p4*4]) = y;
  }
}

// K5: pooled stats per (b,cc): for k in {3,5,7}: mean of avgpool, max of avgpool
__global__ __launch_bounds__(256) void k5_pool(
    const float* __restrict__ yfad, const float* __restrict__ ylfs,
    float* __restrict__ avgstat, float* __restrict__ maxstat)
{
  const int cc = blockIdx.x, b = blockIdx.y;
  const float* src = (cc < 64) ? (yfad + ((size_t)b*64 + cc)*PP)
                               : (ylfs + ((size_t)b*64 + (cc-64))*PP);
  __shared__ float xs[112][113];
  __shared__ float redS[4], redM[4];
  const int tid = threadIdx.x, lane = tid & 63, wave = tid >> 6;
  for (int p = tid; p < PP; p += 256) xs[p/112][p%112] = src[p];
  __syncthreads();
  const int kk[3] = {3,5,7};
  const int gg[3] = {37,22,16};
  for (int ki = 0; ki < 3; ++ki){
    const int k = kk[ki], g = gg[ki];
    float sumAll = 0.f, mx = -3.0e38f;
    for (int win = tid; win < g*g; win += 256){
      int wy = win / g, wx = win % g;
      float s = 0.f;
      for (int dy = 0; dy < k; ++dy)
        for (int dx = 0; dx < k; ++dx)
          s += xs[wy*k+dy][wx*k+dx];
      sumAll += s; mx = fmaxf(mx, s);
    }
    #pragma unroll
    for (int off = 32; off; off >>= 1){
      sumAll += __shfl_xor(sumAll, off, 64);
      mx = fmaxf(mx, __shfl_xor(mx, off, 64));
    }
    if (lane == 0){ redS[wave] = sumAll; redM[wave] = mx; }
    __syncthreads();
    if (tid == 0){
      float st = redS[0]+redS[1]+redS[2]+redS[3];
      float mt = fmaxf(fmaxf(redM[0],redM[1]), fmaxf(redM[2],redM[3]));
      int idx = (b*128 + cc)*3 + ki;
      avgstat[idx] = st / (float)(k*k*g*g);
      maxstat[idx] = mt / (float)(k*k);
    }
    __syncthreads();
  }
}

// K6: channel attention MLP -> ca[b, 128]
__global__ void k6_mlp(const float* __restrict__ avgstat, const float* __restrict__ maxstat,
    const float* __restrict__ lin1, const float* __restrict__ lin2,
    const float* __restrict__ w1, const float* __restrict__ w2,
    float* __restrict__ ca)
{
  const int b = blockIdx.x, tid = threadIdx.x; // 128 threads
  __shared__ float sa[128], sm[128], hA[16], hM[16];
  int idx = (b*128 + tid)*3;
  sa[tid] = avgstat[idx]*lin1[0] + avgstat[idx+1]*lin1[1] + avgstat[idx+2]*lin1[2];
  sm[tid] = maxstat[idx]*lin2[0] + maxstat[idx+1]*lin2[1] + maxstat[idx+2]*lin2[2];
  __syncthreads();
  if (tid < 16){
    float ha = 0.f, hm = 0.f;
    for (int c2 = 0; c2 < 128; ++c2){
      ha += w1[tid*128 + c2]*sa[c2];
      hm += w1[tid*128 + c2]*sm[c2];
    }
    hA[tid] = fmaxf(ha, 0.f); hM[tid] = fmaxf(hm, 0.f);
  }
  __syncthreads();
  float o = 0.f;
  for (int r = 0; r < 16; ++r) o += w2[tid*16 + r]*(hA[r] + hM[r]);
  ca[b*128 + tid] = 1.f/(1.f + __expf(-o));
}

// K7: per-channel sum/sumsq of x = ca_scale * y  (z=0: r_c*y_fad; z=1: f_c*y_lfs)
__global__ __launch_bounds__(256) void k7_statsF(
    const float* __restrict__ yfad, const float* __restrict__ ylfs,
    const float* __restrict__ ca, float* __restrict__ statsF)
{
  const int c = blockIdx.x, b = blockIdx.y, z = blockIdx.z;
  const size_t plane = ((size_t)b*64 + c)*PP;
  const float* y = z ? ylfs : yfad;
  const float sc = ca[b*128 + z*64 + c];
  float s = 0.f, q = 0.f;
  for (int p4 = threadIdx.x; p4 < 3136; p4 += 256){
    float4 yv = *(const float4*)(&y[plane + (size_t)p4*4]);
    float x0 = sc*yv.x, x1 = sc*yv.y, x2 = sc*yv.z, x3 = sc*yv.w;
    s += x0+x1+x2+x3;
    q += x0*x0 + x1*x1 + x2*x2 + x3*x3;
  }
  const int tid = threadIdx.x, lane = tid & 63, wave = tid >> 6;
  #pragma unroll
  for (int off = 32; off; off >>= 1){ s += __shfl_xor(s, off, 64); q += __shfl_xor(q, off, 64); }
  __shared__ float rs[4], rq[4];
  if (lane == 0){ rs[wave] = s; rq[wave] = q; }
  __syncthreads();
  if (tid == 0){
    atomicAdd(&statsF[z*128 + c],      rs[0]+rs[1]+rs[2]+rs[3]);
    atomicAdd(&statsF[z*128 + 64 + c], rq[0]+rq[1]+rq[2]+rq[3]);
  }
}

// K8: fold final bn stats into affine
__global__ void k8_affineF(const float* __restrict__ statsF,
    const float* __restrict__ rgb_cw, const float* __restrict__ rgb_cb,
    const float* __restrict__ rgb_bg, const float* __restrict__ rgb_bb,
    const float* __restrict__ fre_cw, const float* __restrict__ fre_cb,
    const float* __restrict__ fre_bg, const float* __restrict__ fre_bb,
    float* __restrict__ ABF)
{
  int c = threadIdx.x;
  if (c >= 64) return;
  const float n = 401408.f;
  {
    float m = statsF[c]/n, v = statsF[64+c]/n - m*m;
    float cw = rgb_cw[c], g = rgb_bg[c];
    float rs = rsqrtf(cw*cw*v + EPSV);
    ABF[c]      = cw*rs*g;
    ABF[64 + c] = -cw*m*rs*g + rgb_bb[c];
    (void)rgb_cb;
  }
  {
    float m = statsF[128+c]/n, v = statsF[192+c]/n - m*m;
    float cw = fre_cw[c], g = fre_bg[c];
    float rs = rsqrtf(cw*cw*v + EPSV);
    ABF[128 + c] = cw*rs*g;
    ABF[192 + c] = -cw*m*rs*g + fre_bb[c];
    (void)fre_cb;
  }
}

// K9: out = y*(1 + A*ca_scale) + B   (in place over y which lives in d_out)
__global__ __launch_bounds__(256) void k9_out(
    const float* __restrict__ yfad, const float* __restrict__ ylfs,
    const float* __restrict__ ca, const float* __restrict__ ABF,
    float* __restrict__ out)
{
  const int c = blockIdx.x, b = blockIdx.y, z = blockIdx.z;
  const size_t plane = ((size_t)b*64 + c)*PP;
  const float* y = z ? ylfs : yfad;
  float* o = out + (z ? NE : 0) + plane;
  const float sc = ca[b*128 + z*64 + c];
  const float A = ABF[z*128 + c], Bv = ABF[z*128 + 64 + c];
  const float mul = 1.f + A*sc;
  for (int p4 = threadIdx.x; p4 < 3136; p4 += 256){
    float4 yv = *(const float4*)(&y[plane + (size_t)p4*4]);
    float4 ov;
    ov.x = yv.x*mul + Bv;
    ov.y = yv.y*mul + Bv;
    ov.z = yv.z*mul + Bv;
    ov.w = yv.w*mul + Bv;
    *(float4*)(&o[(size_t)p4*4]) = ov;
  }
}

extern "C" void kernel_launch(void* const* d_in, const int* in_sizes, int n_in,
                              void* d_out, int out_size, void* d_ws, size_t ws_size,
                              hipStream_t stream)
{
  (void)in_sizes; (void)n_in; (void)out_size; (void)ws_size;
  const float* rgb      = (const float*)d_in[0];
  const float* fre      = (const float*)d_in[1];
  const float* wq_fad   = (const float*)d_in[2];
  const float* bq_fad   = (const float*)d_in[3];
  const float* wq_lfs   = (const float*)d_in[4];
  const float* bq_lfs   = (const float*)d_in[5];
  const float* wk_fad   = (const float*)d_in[6];
  const float* bk_fad   = (const float*)d_in[7];
  const float* wk_lfs   = (const float*)d_in[8];
  const float* bk_lfs   = (const float*)d_in[9];
  const float* fad_gamma= (const float*)d_in[10];
  const float* lfs_gamma= (const float*)d_in[11];
  const float* fad_cw   = (const float*)d_in[12];
  const float* fad_cb   = (const float*)d_in[13];
  const float* fad_bg   = (const float*)d_in[14];
  const float* fad_bb   = (const float*)d_in[15];
  const float* lfs_cw   = (const float*)d_in[16];
  const float* lfs_cb   = (const float*)d_in[17];
  const float* lfs_bg   = (const float*)d_in[18];
  const float* lfs_bb   = (const float*)d_in[19];
  const float* lin1_w   = (const float*)d_in[20];
  const float* lin2_w   = (const float*)d_in[21];
  const float* mlp_w1   = (const float*)d_in[22];
  const float* mlp_w2   = (const float*)d_in[23];
  const float* rgb_cw   = (const float*)d_in[24];
  const float* rgb_cb   = (const float*)d_in[25];
  const float* rgb_bg   = (const float*)d_in[26];
  const float* rgb_bb   = (const float*)d_in[27];
  const float* fre_cw   = (const float*)d_in[28];
  const float* fre_cb   = (const float*)d_in[29];
  const float* fre_bg   = (const float*)d_in[30];
  const float* fre_bb   = (const float*)d_in[31];

  char* ws = (char*)d_ws;
  unsigned short* qF = (unsigned short*)(ws);
  unsigned short* qL = (unsigned short*)(ws + 2*NE);
  unsigned short* kF = (unsigned short*)(ws + 4*NE);
  unsigned short* kL = (unsigned short*)(ws + 6*NE);
  float* stats = (float*)(ws + 8*NE);
  // t1/t2 (later y_fad/y_lfs) live in d_out; fully rewritten each call.
  float* t1 = (float*)d_out;
  float* t2 = (float*)d_out + NE;

  hipMemsetAsync(stats, 0, 512*sizeof(float), stream);  // bn accumulators only

  k1_conv<<<dim3(98,32,2), dim3(256), 0, stream>>>(rgb, fre,
      wq_fad, bq_fad, wk_fad, bk_fad, wq_lfs, bq_lfs, wk_lfs, bk_lfs,
      qF, kF, qL, kL);
  k2_attn<<<dim3(2048), dim3(256), 0, stream>>>(qF, qL, kF, kL,
      rgb, fre, fad_gamma, lfs_gamma, t1, t2, stats);
  k3_affine1<<<dim3(1), dim3(64), 0, stream>>>(stats,
      fad_cw, fad_cb, fad_bg, fad_bb, lfs_cw, lfs_cb, lfs_bg, lfs_bb, stats + 512);
  k4_y<<<dim3(64,32,2), dim3(256), 0, stream>>>(rgb, fre, t1, t2, stats + 512);
  k5_pool<<<dim3(128,32), dim3(256), 0, stream>>>(t1, t2, stats + 1024, stats + 13312);
  k6_mlp<<<dim3(32), dim3(128), 0, stream>>>(stats + 1024, stats + 13312,
      lin1_w, lin2_w, mlp_w1, mlp_w2, stats + 25600);
  k7_statsF<<<dim3(64,32,2), dim3(256), 0, stream>>>(t1, t2, stats + 25600, stats + 256);
  k8_affineF<<<dim3(1), dim3(64), 0, stream>>>(stats + 256,
      rgb_cw, rgb_cb, rgb_bg, rgb_bb, fre_cw, fre_cb, fre_bg, fre_bb, stats + 768);
  k9_out<<<dim3(64,32,2), dim3(256), 0, stream>>>(t1, t2, stats + 25600, stats + 768,
      (float*)d_out);
}

// Round 2
// 552.572 us; speedup vs baseline: 1.7781x; 1.7781x over previous
//
#include <hip/hip_runtime.h>
#include <hip/hip_bf16.h>
#include <stdint.h>

#define NE 25690112ull   // 32*64*112*112
#define PP 12544         // 112*112
#define SS 112
#define EPSV 1e-5f

typedef __attribute__((ext_vector_type(8))) short short8v;
typedef __attribute__((ext_vector_type(4))) float float4v;

__device__ __forceinline__ unsigned short f2bf(float x){
  union { float f; uint32_t u; } v; v.f = x;
  uint32_t r = (v.u + 0x7fffu + ((v.u >> 16) & 1u)) >> 16;
  return (unsigned short)r;
}
__device__ __forceinline__ float bf2f(unsigned short u){ return __uint_as_float(((uint32_t)u) << 16); }
__device__ __forceinline__ float bflo(uint32_t u){ return __uint_as_float(u << 16); }
__device__ __forceinline__ float bfhi(uint32_t u){ return __uint_as_float(u & 0xffff0000u); }

// ---------------- K1: conv1x1 GEMM (fp32 VALU, unchanged from round 0) ---------------
__global__ __launch_bounds__(256) void k1_conv(
    const float* __restrict__ rgb, const float* __restrict__ fre,
    const float* __restrict__ wq_fad, const float* __restrict__ bq_fad,
    const float* __restrict__ wk_fad, const float* __restrict__ bk_fad,
    const float* __restrict__ wq_lfs, const float* __restrict__ bq_lfs,
    const float* __restrict__ wk_lfs, const float* __restrict__ bk_lfs,
    unsigned short* __restrict__ qF, unsigned short* __restrict__ kF,
    unsigned short* __restrict__ qL, unsigned short* __restrict__ kL)
{
  const int pt = blockIdx.x, b = blockIdx.y, z = blockIdx.z;
  const float* X  = z ? fre : rgb;
  const float* Wq = z ? wq_lfs : wq_fad;
  const float* Bq = z ? bq_lfs : bq_fad;
  const float* Wk = z ? wk_lfs : wk_fad;
  const float* Bk = z ? bk_lfs : bk_fad;
  unsigned short* Oq = z ? qL : qF;
  unsigned short* Ok = z ? kL : kF;

  __shared__ float Xs[64][128];
  __shared__ float Wqs[64][64];
  __shared__ float Wks[64][64];
  const int tid = threadIdx.x;
  for (int i = tid; i < 4096; i += 256){
    int o = i >> 6, c = i & 63;
    Wqs[c][o] = Wq[i];
    Wks[c][o] = Wk[i];
  }
  const int p0 = pt * 128;
  const size_t baseX = ((size_t)b * 64) * PP + p0;
  for (int i = tid; i < 8192; i += 256){
    int c = i >> 7, p = i & 127;
    Xs[c][p] = X[baseX + (size_t)c * PP + p];
  }
  __syncthreads();
  const int tx = tid & 31, oy = tid >> 5;
  float accq[8][4], acck[8][4];
  #pragma unroll
  for (int o = 0; o < 8; ++o){
    float bq = Bq[oy*8+o], bk = Bk[oy*8+o];
    #pragma unroll
    for (int p = 0; p < 4; ++p){ accq[o][p] = bq; acck[o][p] = bk; }
  }
  #pragma unroll 4
  for (int c = 0; c < 64; ++c){
    const float4 xv = *(const float4*)(&Xs[c][tx*4]);
    const float4 a0 = *(const float4*)(&Wqs[c][oy*8]);
    const float4 a1 = *(const float4*)(&Wqs[c][oy*8+4]);
    const float4 b0 = *(const float4*)(&Wks[c][oy*8]);
    const float4 b1 = *(const float4*)(&Wks[c][oy*8+4]);
    float xx[4] = {xv.x, xv.y, xv.z, xv.w};
    float wq[8] = {a0.x,a0.y,a0.z,a0.w,a1.x,a1.y,a1.z,a1.w};
    float wk[8] = {b0.x,b0.y,b0.z,b0.w,b1.x,b1.y,b1.z,b1.w};
    #pragma unroll
    for (int o = 0; o < 8; ++o)
      #pragma unroll
      for (int p = 0; p < 4; ++p){
        accq[o][p] = fmaf(wq[o], xx[p], accq[o][p]);
        acck[o][p] = fmaf(wk[o], xx[p], acck[o][p]);
      }
  }
  #pragma unroll
  for (int o = 0; o < 8; ++o){
    size_t off = ((size_t)b*64 + oy*8+o) * PP + p0 + tx*4;
    ushort4 sq, sk;
    sq.x = f2bf(accq[o][0]); sq.y = f2bf(accq[o][1]); sq.z = f2bf(accq[o][2]); sq.w = f2bf(accq[o][3]);
    sk.x = f2bf(acck[o][0]); sk.y = f2bf(acck[o][1]); sk.z = f2bf(acck[o][2]); sk.w = f2bf(acck[o][3]);
    *(ushort4*)(&Oq[off]) = sq;
    *(ushort4*)(&Ok[off]) = sk;
  }
}

// ---------------- K2: MFMA attention ----------------
// Per (b,c): logits[112][112] = qF.kF^T + qL.kL^T (K padded 112->128 with zeros),
// in-register wave softmax, attn (bf16, RNE) written OVER the qF plane (block-local,
// wave-local rows => race-free), bn1 sum/sumsq of t1=fre*attn*sL, t2=rgb*attn*sF
// accumulated via atomics into stats[0..255].
__global__ __launch_bounds__(448) void k2_attn(
    unsigned short* __restrict__ qF, const unsigned short* __restrict__ qL,
    const unsigned short* __restrict__ kF, const unsigned short* __restrict__ kL,
    const float* __restrict__ rgb, const float* __restrict__ fre,
    const float* __restrict__ fad_gamma, const float* __restrict__ lfs_gamma,
    float* __restrict__ stats)
{
  const int bc = blockIdx.x, c = bc & 63;
  const size_t plane = (size_t)bc * PP;
  __shared__ __align__(16) unsigned short ksF[112][128];  // XOR-swizzled 16B slots
  __shared__ __align__(16) unsigned short ksL[112][128];
  const int tid = threadIdx.x, lane = tid & 63, w = tid >> 6;
  const int l4 = lane >> 4, lc = lane & 15;

  // stage K (both halves), zero-pad cols 112..127, swizzle byte ^= (row&7)<<4
  const uint32_t* kFu = (const uint32_t*)kF + plane/2;
  const uint32_t* kLu = (const uint32_t*)kL + plane/2;
  for (int i = tid; i < 7168; i += 448){
    int row = i >> 6, wd = i & 63;
    uint32_t vF = (wd < 56) ? kFu[row*56 + wd] : 0u;
    uint32_t vL = (wd < 56) ? kLu[row*56 + wd] : 0u;
    uint32_t byteS = (uint32_t)((row << 8) | (wd << 2)) ^ (uint32_t)((row & 7) << 4);
    *(uint32_t*)((char*)&ksF[0][0] + byteS) = vF;
    *(uint32_t*)((char*)&ksL[0][0] + byteS) = vL;
  }
  __syncthreads();

  float4v acc[7];
  #pragma unroll
  for (int ct = 0; ct < 7; ++ct) acc[ct] = (float4v)0.f;

  const unsigned short* qFp = qF + plane;
  const unsigned short* qLp = qL + plane;
  const int qrow = w*16 + lc;   // A-frag row for this lane
  #pragma unroll
  for (int ks = 0; ks < 4; ++ks){
    short8v aF = (short8v)(short)0, aL = (short8v)(short)0;
    const int joff = ks*32 + l4*8;
    if ((ks < 3) || (l4 < 2)){   // j<112 only; B side is zero-padded so product matches
      aF = *(const short8v*)(qFp + qrow*SS + joff);
      aL = *(const short8v*)(qLp + qrow*SS + joff);
    }
    #pragma unroll
    for (int ct = 0; ct < 7; ++ct){
      uint32_t byteS = (uint32_t)((ct*16 + lc)*256 + ks*64 + l4*16) ^ (uint32_t)((lc & 7) << 4);
      short8v bF = *(const short8v*)((const char*)&ksF[0][0] + byteS);
      short8v bL = *(const short8v*)((const char*)&ksL[0][0] + byteS);
      acc[ct] = __builtin_amdgcn_mfma_f32_16x16x32_bf16(aF, bF, acc[ct], 0, 0, 0);
      acc[ct] = __builtin_amdgcn_mfma_f32_16x16x32_bf16(aL, bL, acc[ct], 0, 0, 0);
    }
  }

  const float sF = 2.f/(1.f + __expf(-fad_gamma[0])) - 1.f;
  const float sL = 2.f/(1.f + __expf(-lfs_gamma[0])) - 1.f;
  float ls1 = 0.f, lq1 = 0.f, ls2 = 0.f, lq2 = 0.f;
  unsigned short* attnP = qF + plane;   // overwrite own q-plane (all A-frag reads done)

  #pragma unroll
  for (int r = 0; r < 4; ++r){
    const int i = w*16 + l4*4 + r;      // logits row held by this lane
    float v[7];
    #pragma unroll
    for (int ct = 0; ct < 7; ++ct) v[ct] = acc[ct][r];
    float m = fmaxf(fmaxf(fmaxf(v[0],v[1]),fmaxf(v[2],v[3])), fmaxf(fmaxf(v[4],v[5]),v[6]));
    #pragma unroll
    for (int off = 8; off; off >>= 1) m = fmaxf(m, __shfl_xor(m, off, 64));
    float e[7]; float s = 0.f;
    #pragma unroll
    for (int ct = 0; ct < 7; ++ct){ e[ct] = __expf(v[ct] - m); s += e[ct]; }
    #pragma unroll
    for (int off = 8; off; off >>= 1) s += __shfl_xor(s, off, 64);
    const float inv = 1.f / s;
    const size_t rb = plane + (size_t)i * SS;
    #pragma unroll
    for (int ct = 0; ct < 7; ++ct){
      const int col = ct*16 + lc;
      unsigned short ab = f2bf(e[ct] * inv);
      attnP[(size_t)i*SS + col] = ab;
      float a  = bf2f(ab);               // stats from ROUNDED attn (matches k4)
      float frv = fre[rb + col], rgv = rgb[rb + col];
      float v1 = frv * a * sL, v2 = rgv * a * sF;
      ls1 += v1; lq1 += v1*v1; ls2 += v2; lq2 += v2*v2;
    }
  }
  #pragma unroll
  for (int off = 32; off; off >>= 1){
    ls1 += __shfl_xor(ls1, off, 64);
    lq1 += __shfl_xor(lq1, off, 64);
    ls2 += __shfl_xor(ls2, off, 64);
    lq2 += __shfl_xor(lq2, off, 64);
  }
  if (lane == 0){
    atomicAdd(&stats[c],       ls1);
    atomicAdd(&stats[64 + c],  lq1);
    atomicAdd(&stats[128 + c], ls2);
    atomicAdd(&stats[192 + c], lq2);
  }
}

// ---------------- K3: bn1 stats -> affine ----------------
__global__ void k3_affine1(const float* __restrict__ stats,
    const float* __restrict__ fad_cw, const float* __restrict__ fad_bg, const float* __restrict__ fad_bb,
    const float* __restrict__ lfs_cw, const float* __restrict__ lfs_bg, const float* __restrict__ lfs_bb,
    float* __restrict__ AB)
{
  int c = threadIdx.x;
  if (c >= 64) return;
  const float n = 401408.f;
  {
    float m1 = stats[c]/n, v1 = stats[64+c]/n - (stats[c]/n)*(stats[c]/n);
    float cw = fad_cw[c], g = fad_bg[c];
    float rs = rsqrtf(cw*cw*v1 + EPSV);
    AB[c]      = cw*rs*g;
    AB[64 + c] = -cw*m1*rs*g + fad_bb[c];
  }
  {
    float m2 = stats[128+c]/n, v2 = stats[192+c]/n - (stats[128+c]/n)*(stats[128+c]/n);
    float cw = lfs_cw[c], g = lfs_bg[c];
    float rs = rsqrtf(cw*cw*v2 + EPSV);
    AB[128 + c] = cw*rs*g;
    AB[192 + c] = -cw*m2*rs*g + lfs_bb[c];
  }
}

// ---------------- K4: fused y + pooling + per-plane stats ----------------
// One block per (b,c): y_fad = rgb + A1*(fre*attn*sL)+B1 ; y_lfs = fre + A2*(rgb*attn*sF)+B2
// writes both planes, keeps bf16 copies in LDS for the 3 pools, emits per-plane sum/sumsq.
__global__ __launch_bounds__(512) void k4_fuse(
    const unsigned short* __restrict__ attn,
    const float* __restrict__ rgb, const float* __restrict__ fre,
    const float* __restrict__ AB1,
    const float* __restrict__ fad_gamma, const float* __restrict__ lfs_gamma,
    float* __restrict__ yfad, float* __restrict__ ylfs,
    float* __restrict__ avgstat, float* __restrict__ maxstat,
    float4* __restrict__ planeStats)
{
  const int bc = blockIdx.x, b = bc >> 6, c = bc & 63;
  const size_t plane = (size_t)bc * PP;
  __shared__ unsigned short ys[2][112][113];
  __shared__ float redA[8][4];
  __shared__ float redS[8], redM[8];
  const int tid = threadIdx.x, lane = tid & 63, w = tid >> 6;
  const float sF = 2.f/(1.f + __expf(-fad_gamma[0])) - 1.f;
  const float sL = 2.f/(1.f + __expf(-lfs_gamma[0])) - 1.f;
  const float A1 = AB1[c], B1 = AB1[64+c], A2 = AB1[128+c], B2 = AB1[192+c];
  float s0 = 0.f, q0 = 0.f, s1 = 0.f, q1 = 0.f;

  for (int i4 = tid; i4 < 3136; i4 += 512){
    ushort4 av = *(const ushort4*)(attn + plane + (size_t)i4*4);
    float4 rg = *(const float4*)(rgb + plane + (size_t)i4*4);
    float4 fr = *(const float4*)(fre + plane + (size_t)i4*4);
    float aa[4] = {bf2f(av.x), bf2f(av.y), bf2f(av.z), bf2f(av.w)};
    float rr[4] = {rg.x, rg.y, rg.z, rg.w};
    float ff[4] = {fr.x, fr.y, fr.z, fr.w};
    float y0[4], y1[4];
    #pragma unroll
    for (int j = 0; j < 4; ++j){
      float t1 = ff[j]*aa[j]*sL;
      float t2 = rr[j]*aa[j]*sF;
      y0[j] = rr[j] + A1*t1 + B1;
      y1[j] = ff[j] + A2*t2 + B2;
      s0 += y0[j]; q0 += y0[j]*y0[j];
      s1 += y1[j]; q1 += y1[j]*y1[j];
    }
    float4 o0 = {y0[0],y0[1],y0[2],y0[3]};
    float4 o1 = {y1[0],y1[1],y1[2],y1[3]};
    *(float4*)(yfad + plane + (size_t)i4*4) = o0;
    *(float4*)(ylfs + plane + (size_t)i4*4) = o1;
    int r = i4 / 28, c0 = (i4 % 28) * 4;   // 112 = 28*4, groups never cross rows
    #pragma unroll
    for (int j = 0; j < 4; ++j){
      ys[0][r][c0+j] = f2bf(y0[j]);
      ys[1][r][c0+j] = f2bf(y1[j]);
    }
  }
  #pragma unroll
  for (int off = 32; off; off >>= 1){
    s0 += __shfl_xor(s0, off, 64); q0 += __shfl_xor(q0, off, 64);
    s1 += __shfl_xor(s1, off, 64); q1 += __shfl_xor(q1, off, 64);
  }
  if (lane == 0){ redA[w][0] = s0; redA[w][1] = q0; redA[w][2] = s1; redA[w][3] = q1; }
  __syncthreads();
  if (tid == 0){
    float a0=0,a1=0,a2=0,a3=0;
    for (int i = 0; i < 8; ++i){ a0+=redA[i][0]; a1+=redA[i][1]; a2+=redA[i][2]; a3+=redA[i][3]; }
    float4 ps = {a0,a1,a2,a3};
    planeStats[bc] = ps;
  }
  __syncthreads();

  const int kk[3] = {3,5,7};
  const int gg[3] = {37,22,16};
  for (int pl = 0; pl < 2; ++pl){
    const int cc = pl*64 + c;
    for (int ki = 0; ki < 3; ++ki){
      const int k = kk[ki], g = gg[ki];
      float sumAll = 0.f, mx = -3.0e38f;
      for (int win = tid; win < g*g; win += 512){
        int wy = win / g, wx = win % g;
        float s = 0.f;
        for (int dy = 0; dy < k; ++dy)
          for (int dx = 0; dx < k; ++dx)
            s += bf2f(ys[pl][wy*k+dy][wx*k+dx]);
        sumAll += s; mx = fmaxf(mx, s);
      }
      #pragma unroll
      for (int off = 32; off; off >>= 1){
        sumAll += __shfl_xor(sumAll, off, 64);
        mx = fmaxf(mx, __shfl_xor(mx, off, 64));
      }
      if (lane == 0){ redS[w] = sumAll; redM[w] = mx; }
      __syncthreads();
      if (tid == 0){
        float st = 0.f, mt = -3.0e38f;
        for (int i = 0; i < 8; ++i){ st += redS[i]; mt = fmaxf(mt, redM[i]); }
        int idx = (b*128 + cc)*3 + ki;
        avgstat[idx] = st / (float)(k*k*g*g);
        maxstat[idx] = mt / (float)(k*k);
      }
      __syncthreads();
    }
  }
}

// ---------------- K6: channel-attention MLP ----------------
__global__ void k6_mlp(const float* __restrict__ avgstat, const float* __restrict__ maxstat,
    const float* __restrict__ lin1, const float* __restrict__ lin2,
    const float* __restrict__ w1, const float* __restrict__ w2,
    float* __restrict__ ca)
{
  const int b = blockIdx.x, tid = threadIdx.x; // 128 threads
  __shared__ float sa[128], sm[128], hA[16], hM[16];
  int idx = (b*128 + tid)*3;
  sa[tid] = avgstat[idx]*lin1[0] + avgstat[idx+1]*lin1[1] + avgstat[idx+2]*lin1[2];
  sm[tid] = maxstat[idx]*lin2[0] + maxstat[idx+1]*lin2[1] + maxstat[idx+2]*lin2[2];
  __syncthreads();
  if (tid < 16){
    float ha = 0.f, hm = 0.f;
    for (int c2 = 0; c2 < 128; ++c2){
      ha += w1[tid*128 + c2]*sa[c2];
      hm += w1[tid*128 + c2]*sm[c2];
    }
    hA[tid] = fmaxf(ha, 0.f); hM[tid] = fmaxf(hm, 0.f);
  }
  __syncthreads();
  float o = 0.f;
  for (int r = 0; r < 16; ++r) o += w2[tid*16 + r]*(hA[r] + hM[r]);
  ca[b*128 + tid] = 1.f/(1.f + __expf(-o));
}

// ---------------- K8: final bn affine from per-plane stats + ca ----------------
__global__ void k8_affineF(const float4* __restrict__ planeStats, const float* __restrict__ ca,
    const float* __restrict__ rgb_cw, const float* __restrict__ rgb_bg, const float* __restrict__ rgb_bb,
    const float* __restrict__ fre_cw, const float* __restrict__ fre_bg, const float* __restrict__ fre_bb,
    float* __restrict__ ABF)
{
  int t = threadIdx.x;
  if (t >= 128) return;
  int z = t >> 6, c = t & 63;
  float S = 0.f, Q = 0.f;
  for (int b = 0; b < 32; ++b){
    float4 ps = planeStats[b*64 + c];
    float sc = ca[b*128 + t];
    float sp = z ? ps.z : ps.x;
    float qp = z ? ps.w : ps.y;
    S += sc*sp; Q += sc*sc*qp;
  }
  const float n = 401408.f;
  float m = S/n, v = Q/n - m*m;
  float cw = z ? fre_cw[c] : rgb_cw[c];
  float g  = z ? fre_bg[c] : rgb_bg[c];
  float bb = z ? fre_bb[c] : rgb_bb[c];
  float rs = rsqrtf(cw*cw*v + EPSV);
  ABF[z*128 + c]      = cw*rs*g;
  ABF[z*128 + 64 + c] = -cw*m*rs*g + bb;
}

// ---------------- K9: out = y*(1 + A*ca) + B (in place) ----------------
__global__ __launch_bounds__(256) void k9_out(
    const float* __restrict__ yfad, const float* __restrict__ ylfs,
    const float* __restrict__ ca, const float* __restrict__ ABF,
    float* __restrict__ out)
{
  const int c = blockIdx.x, b = blockIdx.y, z = blockIdx.z;
  const size_t plane = ((size_t)b*64 + c)*PP;
  const float* y = z ? ylfs : yfad;
  float* o = out + (z ? NE : 0) + plane;
  const float sc = ca[b*128 + z*64 + c];
  const float A = ABF[z*128 + c], Bv = ABF[z*128 + 64 + c];
  const float mul = 1.f + A*sc;
  for (int p4 = threadIdx.x; p4 < 3136; p4 += 256){
    float4 yv = *(const float4*)(&y[plane + (size_t)p4*4]);
    float4 ov;
    ov.x = yv.x*mul + Bv;
    ov.y = yv.y*mul + Bv;
    ov.z = yv.z*mul + Bv;
    ov.w = yv.w*mul + Bv;
    *(float4*)(&o[(size_t)p4*4]) = ov;
  }
}

extern "C" void kernel_launch(void* const* d_in, const int* in_sizes, int n_in,
                              void* d_out, int out_size, void* d_ws, size_t ws_size,
                              hipStream_t stream)
{
  (void)in_sizes; (void)n_in; (void)out_size; (void)ws_size;
  const float* rgb      = (const float*)d_in[0];
  const float* fre      = (const float*)d_in[1];
  const float* wq_fad   = (const float*)d_in[2];
  const float* bq_fad   = (const float*)d_in[3];
  const float* wq_lfs   = (const float*)d_in[4];
  const float* bq_lfs   = (const float*)d_in[5];
  const float* wk_fad   = (const float*)d_in[6];
  const float* bk_fad   = (const float*)d_in[7];
  const float* wk_lfs   = (const float*)d_in[8];
  const float* bk_lfs   = (const float*)d_in[9];
  const float* fad_gamma= (const float*)d_in[10];
  const float* lfs_gamma= (const float*)d_in[11];
  const float* fad_cw   = (const float*)d_in[12];
  const float* fad_bg   = (const float*)d_in[14];
  const float* fad_bb   = (const float*)d_in[15];
  const float* lfs_cw   = (const float*)d_in[16];
  const float* lfs_bg   = (const float*)d_in[18];
  const float* lfs_bb   = (const float*)d_in[19];
  const float* lin1_w   = (const float*)d_in[20];
  const float* lin2_w   = (const float*)d_in[21];
  const float* mlp_w1   = (const float*)d_in[22];
  const float* mlp_w2   = (const float*)d_in[23];
  const float* rgb_cw   = (const float*)d_in[24];
  const float* rgb_bg   = (const float*)d_in[26];
  const float* rgb_bb   = (const float*)d_in[27];
  const float* fre_cw   = (const float*)d_in[28];
  const float* fre_bg   = (const float*)d_in[30];
  const float* fre_bb   = (const float*)d_in[31];

  char* ws = (char*)d_ws;
  unsigned short* qF = (unsigned short*)(ws);          // becomes attn after k2
  unsigned short* qL = (unsigned short*)(ws + 2*NE);
  unsigned short* kF = (unsigned short*)(ws + 4*NE);
  unsigned short* kL = (unsigned short*)(ws + 6*NE);
  float* sbase = (float*)(ws + 8*NE);
  float* stats      = sbase;               // [0..255]   bn1 atomics (memset)
  float* AB1        = sbase + 256;         // [256..511]
  float* avgstat    = sbase + 512;         // 12288
  float* maxstat    = sbase + 12800;       // 12288
  float* ca         = sbase + 25088;       // 4096
  float* ABF        = sbase + 29184;       // 256
  float4* planeStats= (float4*)(sbase + 29440); // 2048 float4
  float* yfad = (float*)d_out;
  float* ylfs = (float*)d_out + NE;

  hipMemsetAsync(stats, 0, 256*sizeof(float), stream);

  k1_conv<<<dim3(98,32,2), dim3(256), 0, stream>>>(rgb, fre,
      wq_fad, bq_fad, wk_fad, bk_fad, wq_lfs, bq_lfs, wk_lfs, bk_lfs,
      qF, kF, qL, kL);
  k2_attn<<<dim3(2048), dim3(448), 0, stream>>>(qF, qL, kF, kL,
      rgb, fre, fad_gamma, lfs_gamma, stats);
  k3_affine1<<<dim3(1), dim3(64), 0, stream>>>(stats,
      fad_cw, fad_bg, fad_bb, lfs_cw, lfs_bg, lfs_bb, AB1);
  k4_fuse<<<dim3(2048), dim3(512), 0, stream>>>((const unsigned short*)qF,
      rgb, fre, AB1, fad_gamma, lfs_gamma, yfad, ylfs, avgstat, maxstat, planeStats);
  k6_mlp<<<dim3(32), dim3(128), 0, stream>>>(avgstat, maxstat,
      lin1_w, lin2_w, mlp_w1, mlp_w2, ca);
  k8_affineF<<<dim3(1), dim3(128), 0, stream>>>(planeStats, ca,
      rgb_cw, rgb_bg, rgb_bb, fre_cw, fre_bg, fre_bb, ABF);
  k9_out<<<dim3(64,32,2), dim3(256), 0, stream>>>(yfad, ylfs, ca, ABF,
      (float*)d_out);
}

// Round 3
// 477.234 us; speedup vs baseline: 2.0588x; 1.1579x over previous
//
#include <hip/hip_runtime.h>
#include <hip/hip_bf16.h>
#include <stdint.h>

#define NE 25690112ull   // 32*64*112*112
#define PP 12544         // 112*112
#define SS 112
#define EPSV 1e-5f

typedef __attribute__((ext_vector_type(8))) short short8v;
typedef __attribute__((ext_vector_type(4))) float float4v;

__device__ __forceinline__ unsigned short f2bf(float x){
  union { float f; uint32_t u; } v; v.f = x;
  uint32_t r = (v.u + 0x7fffu + ((v.u >> 16) & 1u)) >> 16;
  return (unsigned short)r;
}
__device__ __forceinline__ float bf2f(unsigned short u){ return __uint_as_float(((uint32_t)u) << 16); }

// ---------------- K1: conv1x1 via MFMA, D[p][o] = X^T · W^T ----------------
// Per (b,z): Q[o,p] = sum_c Wq[o,c] X[c,p] + bq[o]; same for K. A = X^T frags
// loaded directly from global (each element once), B = weight frags held in
// registers for the whole block, D stored as ushort4 (4 consecutive p per lane).
__global__ __launch_bounds__(256) void k1_conv(
    const float* __restrict__ rgb, const float* __restrict__ fre,
    const float* __restrict__ wq_fad, const float* __restrict__ bq_fad,
    const float* __restrict__ wk_fad, const float* __restrict__ bk_fad,
    const float* __restrict__ wq_lfs, const float* __restrict__ bq_lfs,
    const float* __restrict__ wk_lfs, const float* __restrict__ bk_lfs,
    unsigned short* __restrict__ qF, unsigned short* __restrict__ kF,
    unsigned short* __restrict__ qL, unsigned short* __restrict__ kL)
{
  const int bx = blockIdx.x, b = blockIdx.y, z = blockIdx.z;
  const float* X  = z ? fre : rgb;
  const float* Wq = z ? wq_lfs : wq_fad;
  const float* Bq = z ? bq_lfs : bq_fad;
  const float* Wk = z ? wk_lfs : wk_fad;
  const float* Bk = z ? bk_lfs : bk_fad;
  unsigned short* Oq = z ? qL : qF;
  unsigned short* Ok = z ? kL : kF;

  const int tid = threadIdx.x, lane = tid & 63, w = tid >> 6;
  const int lc = lane & 15, l4 = lane >> 4;

  // Weight B-frags: lane holds B[k=c][col=o=lc] = W[o=ot*16+lc][c=ks*32+l4*8+j]
  short8v wqf[4][2], wkf[4][2];
  float bq[4], bk[4];
  #pragma unroll
  for (int ot = 0; ot < 4; ++ot){
    bq[ot] = Bq[ot*16 + lc];
    bk[ot] = Bk[ot*16 + lc];
    #pragma unroll
    for (int ks = 0; ks < 2; ++ks){
      const int base = (ot*16 + lc)*64 + ks*32 + l4*8;
      const float4 q0 = *(const float4*)(Wq + base);
      const float4 q1 = *(const float4*)(Wq + base + 4);
      const float4 k0 = *(const float4*)(Wk + base);
      const float4 k1 = *(const float4*)(Wk + base + 4);
      short8v vq, vk;
      vq[0]=(short)f2bf(q0.x); vq[1]=(short)f2bf(q0.y); vq[2]=(short)f2bf(q0.z); vq[3]=(short)f2bf(q0.w);
      vq[4]=(short)f2bf(q1.x); vq[5]=(short)f2bf(q1.y); vq[6]=(short)f2bf(q1.z); vq[7]=(short)f2bf(q1.w);
      vk[0]=(short)f2bf(k0.x); vk[1]=(short)f2bf(k0.y); vk[2]=(short)f2bf(k0.z); vk[3]=(short)f2bf(k0.w);
      vk[4]=(short)f2bf(k1.x); vk[5]=(short)f2bf(k1.y); vk[6]=(short)f2bf(k1.z); vk[7]=(short)f2bf(k1.w);
      wqf[ot][ks] = vq; wkf[ot][ks] = vk;
    }
  }

  const size_t xbase = (size_t)b * 64 * PP;
  #pragma unroll
  for (int t = 0; t < 4; ++t){
    const int p0 = bx*256 + (t*4 + w)*16;
    // A-frags: lane holds A[row=p=p0+lc][k=c=ks*32+l4*8+j], each element read once
    float af[2][8];
    #pragma unroll
    for (int ks = 0; ks < 2; ++ks)
      #pragma unroll
      for (int j = 0; j < 8; ++j)
        af[ks][j] = X[xbase + (size_t)(ks*32 + l4*8 + j)*PP + p0 + lc];
    short8v a0, a1;
    #pragma unroll
    for (int j = 0; j < 8; ++j){ a0[j] = (short)f2bf(af[0][j]); a1[j] = (short)f2bf(af[1][j]); }

    float4v aq[4], ak[4];
    #pragma unroll
    for (int ot = 0; ot < 4; ++ot){
      aq[ot] = (float4v){bq[ot], bq[ot], bq[ot], bq[ot]};
      ak[ot] = (float4v){bk[ot], bk[ot], bk[ot], bk[ot]};
    }
    #pragma unroll
    for (int ot = 0; ot < 4; ++ot){
      aq[ot] = __builtin_amdgcn_mfma_f32_16x16x32_bf16(a0, wqf[ot][0], aq[ot], 0, 0, 0);
      aq[ot] = __builtin_amdgcn_mfma_f32_16x16x32_bf16(a1, wqf[ot][1], aq[ot], 0, 0, 0);
      ak[ot] = __builtin_amdgcn_mfma_f32_16x16x32_bf16(a0, wkf[ot][0], ak[ot], 0, 0, 0);
      ak[ot] = __builtin_amdgcn_mfma_f32_16x16x32_bf16(a1, wkf[ot][1], ak[ot], 0, 0, 0);
    }
    // D: lane holds o=ot*16+lc, p = p0 + l4*4 + reg -> 4 consecutive p = ushort4
    #pragma unroll
    for (int ot = 0; ot < 4; ++ot){
      const size_t off = ((size_t)b*64 + ot*16 + lc)*PP + p0 + l4*4;
      ushort4 sq, sk;
      sq.x = f2bf(aq[ot][0]); sq.y = f2bf(aq[ot][1]); sq.z = f2bf(aq[ot][2]); sq.w = f2bf(aq[ot][3]);
      sk.x = f2bf(ak[ot][0]); sk.y = f2bf(ak[ot][1]); sk.z = f2bf(ak[ot][2]); sk.w = f2bf(ak[ot][3]);
      *(ushort4*)(Oq + off) = sq;
      *(ushort4*)(Ok + off) = sk;
    }
  }
}

// ---------------- K2: MFMA attention (unchanged from round 1) ----------------
__global__ __launch_bounds__(448) void k2_attn(
    unsigned short* __restrict__ qF, const unsigned short* __restrict__ qL,
    const unsigned short* __restrict__ kF, const unsigned short* __restrict__ kL,
    const float* __restrict__ rgb, const float* __restrict__ fre,
    const float* __restrict__ fad_gamma, const float* __restrict__ lfs_gamma,
    float* __restrict__ stats)
{
  const int bc = blockIdx.x, c = bc & 63;
  const size_t plane = (size_t)bc * PP;
  __shared__ __align__(16) unsigned short ksF[112][128];
  __shared__ __align__(16) unsigned short ksL[112][128];
  const int tid = threadIdx.x, lane = tid & 63, w = tid >> 6;
  const int l4 = lane >> 4, lc = lane & 15;

  const uint32_t* kFu = (const uint32_t*)kF + plane/2;
  const uint32_t* kLu = (const uint32_t*)kL + plane/2;
  for (int i = tid; i < 7168; i += 448){
    int row = i >> 6, wd = i & 63;
    uint32_t vF = (wd < 56) ? kFu[row*56 + wd] : 0u;
    uint32_t vL = (wd < 56) ? kLu[row*56 + wd] : 0u;
    uint32_t byteS = (uint32_t)((row << 8) | (wd << 2)) ^ (uint32_t)((row & 7) << 4);
    *(uint32_t*)((char*)&ksF[0][0] + byteS) = vF;
    *(uint32_t*)((char*)&ksL[0][0] + byteS) = vL;
  }
  __syncthreads();

  float4v acc[7];
  #pragma unroll
  for (int ct = 0; ct < 7; ++ct) acc[ct] = (float4v)0.f;

  const unsigned short* qFp = qF + plane;
  const unsigned short* qLp = qL + plane;
  const int qrow = w*16 + lc;
  #pragma unroll
  for (int ks = 0; ks < 4; ++ks){
    short8v aF = (short8v)(short)0, aL = (short8v)(short)0;
    const int joff = ks*32 + l4*8;
    if ((ks < 3) || (l4 < 2)){
      aF = *(const short8v*)(qFp + qrow*SS + joff);
      aL = *(const short8v*)(qLp + qrow*SS + joff);
    }
    #pragma unroll
    for (int ct = 0; ct < 7; ++ct){
      uint32_t byteS = (uint32_t)((ct*16 + lc)*256 + ks*64 + l4*16) ^ (uint32_t)((lc & 7) << 4);
      short8v bF = *(const short8v*)((const char*)&ksF[0][0] + byteS);
      short8v bL = *(const short8v*)((const char*)&ksL[0][0] + byteS);
      acc[ct] = __builtin_amdgcn_mfma_f32_16x16x32_bf16(aF, bF, acc[ct], 0, 0, 0);
      acc[ct] = __builtin_amdgcn_mfma_f32_16x16x32_bf16(aL, bL, acc[ct], 0, 0, 0);
    }
  }

  const float sF = 2.f/(1.f + __expf(-fad_gamma[0])) - 1.f;
  const float sL = 2.f/(1.f + __expf(-lfs_gamma[0])) - 1.f;
  float ls1 = 0.f, lq1 = 0.f, ls2 = 0.f, lq2 = 0.f;
  unsigned short* attnP = qF + plane;

  #pragma unroll
  for (int r = 0; r < 4; ++r){
    const int i = w*16 + l4*4 + r;
    float v[7];
    #pragma unroll
    for (int ct = 0; ct < 7; ++ct) v[ct] = acc[ct][r];
    float m = fmaxf(fmaxf(fmaxf(v[0],v[1]),fmaxf(v[2],v[3])), fmaxf(fmaxf(v[4],v[5]),v[6]));
    #pragma unroll
    for (int off = 8; off; off >>= 1) m = fmaxf(m, __shfl_xor(m, off, 64));
    float e[7]; float s = 0.f;
    #pragma unroll
    for (int ct = 0; ct < 7; ++ct){ e[ct] = __expf(v[ct] - m); s += e[ct]; }
    #pragma unroll
    for (int off = 8; off; off >>= 1) s += __shfl_xor(s, off, 64);
    const float inv = 1.f / s;
    const size_t rb = plane + (size_t)i * SS;
    #pragma unroll
    for (int ct = 0; ct < 7; ++ct){
      const int col = ct*16 + lc;
      unsigned short ab = f2bf(e[ct] * inv);
      attnP[(size_t)i*SS + col] = ab;
      float a  = bf2f(ab);
      float frv = fre[rb + col], rgv = rgb[rb + col];
      float v1 = frv * a * sL, v2 = rgv * a * sF;
      ls1 += v1; lq1 += v1*v1; ls2 += v2; lq2 += v2*v2;
    }
  }
  #pragma unroll
  for (int off = 32; off; off >>= 1){
    ls1 += __shfl_xor(ls1, off, 64);
    lq1 += __shfl_xor(lq1, off, 64);
    ls2 += __shfl_xor(ls2, off, 64);
    lq2 += __shfl_xor(lq2, off, 64);
  }
  if (lane == 0){
    atomicAdd(&stats[c],       ls1);
    atomicAdd(&stats[64 + c],  lq1);
    atomicAdd(&stats[128 + c], ls2);
    atomicAdd(&stats[192 + c], lq2);
  }
}

// ---------------- K3: bn1 stats -> affine ----------------
__global__ void k3_affine1(const float* __restrict__ stats,
    const float* __restrict__ fad_cw, const float* __restrict__ fad_bg, const float* __restrict__ fad_bb,
    const float* __restrict__ lfs_cw, const float* __restrict__ lfs_bg, const float* __restrict__ lfs_bb,
    float* __restrict__ AB)
{
  int c = threadIdx.x;
  if (c >= 64) return;
  const float n = 401408.f;
  {
    float m1 = stats[c]/n, v1 = stats[64+c]/n - (stats[c]/n)*(stats[c]/n);
    float cw = fad_cw[c], g = fad_bg[c];
    float rs = rsqrtf(cw*cw*v1 + EPSV);
    AB[c]      = cw*rs*g;
    AB[64 + c] = -cw*m1*rs*g + fad_bb[c];
  }
  {
    float m2 = stats[128+c]/n, v2 = stats[192+c]/n - (stats[128+c]/n)*(stats[128+c]/n);
    float cw = lfs_cw[c], g = lfs_bg[c];
    float rs = rsqrtf(cw*cw*v2 + EPSV);
    AB[128 + c] = cw*rs*g;
    AB[192 + c] = -cw*m2*rs*g + lfs_bb[c];
  }
}

// ---------------- K4: fused y (bf16 out) + pooling + per-plane stats ----------------
__global__ __launch_bounds__(512) void k4_fuse(
    const unsigned short* __restrict__ attn,
    const float* __restrict__ rgb, const float* __restrict__ fre,
    const float* __restrict__ AB1,
    const float* __restrict__ fad_gamma, const float* __restrict__ lfs_gamma,
    unsigned short* __restrict__ ybf, unsigned short* __restrict__ ybl,
    float* __restrict__ avgstat, float* __restrict__ maxstat,
    float4* __restrict__ planeStats)
{
  const int bc = blockIdx.x, b = bc >> 6, c = bc & 63;
  const size_t plane = (size_t)bc * PP;
  __shared__ unsigned short ys[2][112][113];
  __shared__ float redA[8][4];
  __shared__ float redS[8], redM[8];
  const int tid = threadIdx.x, lane = tid & 63, w = tid >> 6;
  const float sF = 2.f/(1.f + __expf(-fad_gamma[0])) - 1.f;
  const float sL = 2.f/(1.f + __expf(-lfs_gamma[0])) - 1.f;
  const float A1 = AB1[c], B1 = AB1[64+c], A2 = AB1[128+c], B2 = AB1[192+c];
  float s0 = 0.f, q0 = 0.f, s1 = 0.f, q1 = 0.f;

  for (int i4 = tid; i4 < 3136; i4 += 512){
    ushort4 av = *(const ushort4*)(attn + plane + (size_t)i4*4);
    float4 rg = *(const float4*)(rgb + plane + (size_t)i4*4);
    float4 fr = *(const float4*)(fre + plane + (size_t)i4*4);
    float aa[4] = {bf2f(av.x), bf2f(av.y), bf2f(av.z), bf2f(av.w)};
    float rr[4] = {rg.x, rg.y, rg.z, rg.w};
    float ff[4] = {fr.x, fr.y, fr.z, fr.w};
    float y0[4], y1[4];
    ushort4 o0, o1;
    unsigned short* p0 = &o0.x; unsigned short* p1 = &o1.x;
    #pragma unroll
    for (int j = 0; j < 4; ++j){
      float t1 = ff[j]*aa[j]*sL;
      float t2 = rr[j]*aa[j]*sF;
      y0[j] = rr[j] + A1*t1 + B1;
      y1[j] = ff[j] + A2*t2 + B2;
      s0 += y0[j]; q0 += y0[j]*y0[j];
      s1 += y1[j]; q1 += y1[j]*y1[j];
      p0[j] = f2bf(y0[j]);
      p1[j] = f2bf(y1[j]);
    }
    *(ushort4*)(ybf + plane + (size_t)i4*4) = o0;
    *(ushort4*)(ybl + plane + (size_t)i4*4) = o1;
    int r = i4 / 28, c0 = (i4 % 28) * 4;
    #pragma unroll
    for (int j = 0; j < 4; ++j){
      ys[0][r][c0+j] = p0[j];
      ys[1][r][c0+j] = p1[j];
    }
  }
  #pragma unroll
  for (int off = 32; off; off >>= 1){
    s0 += __shfl_xor(s0, off, 64); q0 += __shfl_xor(q0, off, 64);
    s1 += __shfl_xor(s1, off, 64); q1 += __shfl_xor(q1, off, 64);
  }
  if (lane == 0){ redA[w][0] = s0; redA[w][1] = q0; redA[w][2] = s1; redA[w][3] = q1; }
  __syncthreads();
  if (tid == 0){
    float a0=0,a1=0,a2=0,a3=0;
    for (int i = 0; i < 8; ++i){ a0+=redA[i][0]; a1+=redA[i][1]; a2+=redA[i][2]; a3+=redA[i][3]; }
    float4 ps = {a0,a1,a2,a3};
    planeStats[bc] = ps;
  }
  __syncthreads();

  const int kk[3] = {3,5,7};
  const int gg[3] = {37,22,16};
  for (int pl = 0; pl < 2; ++pl){
    const int cc = pl*64 + c;
    for (int ki = 0; ki < 3; ++ki){
      const int k = kk[ki], g = gg[ki];
      float sumAll = 0.f, mx = -3.0e38f;
      for (int win = tid; win < g*g; win += 512){
        int wy = win / g, wx = win % g;
        float s = 0.f;
        for (int dy = 0; dy < k; ++dy)
          for (int dx = 0; dx < k; ++dx)
            s += bf2f(ys[pl][wy*k+dy][wx*k+dx]);
        sumAll += s; mx = fmaxf(mx, s);
      }
      #pragma unroll
      for (int off = 32; off; off >>= 1){
        sumAll += __shfl_xor(sumAll, off, 64);
        mx = fmaxf(mx, __shfl_xor(mx, off, 64));
      }
      if (lane == 0){ redS[w] = sumAll; redM[w] = mx; }
      __syncthreads();
      if (tid == 0){
        float st = 0.f, mt = -3.0e38f;
        for (int i = 0; i < 8; ++i){ st += redS[i]; mt = fmaxf(mt, redM[i]); }
        int idx = (b*128 + cc)*3 + ki;
        avgstat[idx] = st / (float)(k*k*g*g);
        maxstat[idx] = mt / (float)(k*k);
      }
      __syncthreads();
    }
  }
}

// ---------------- K6: channel-attention MLP ----------------
__global__ void k6_mlp(const float* __restrict__ avgstat, const float* __restrict__ maxstat,
    const float* __restrict__ lin1, const float* __restrict__ lin2,
    const float* __restrict__ w1, const float* __restrict__ w2,
    float* __restrict__ ca)
{
  const int b = blockIdx.x, tid = threadIdx.x; // 128 threads
  __shared__ float sa[128], sm[128], hA[16], hM[16];
  int idx = (b*128 + tid)*3;
  sa[tid] = avgstat[idx]*lin1[0] + avgstat[idx+1]*lin1[1] + avgstat[idx+2]*lin1[2];
  sm[tid] = maxstat[idx]*lin2[0] + maxstat[idx+1]*lin2[1] + maxstat[idx+2]*lin2[2];
  __syncthreads();
  if (tid < 16){
    float ha = 0.f, hm = 0.f;
    for (int c2 = 0; c2 < 128; ++c2){
      ha += w1[tid*128 + c2]*sa[c2];
      hm += w1[tid*128 + c2]*sm[c2];
    }
    hA[tid] = fmaxf(ha, 0.f); hM[tid] = fmaxf(hm, 0.f);
  }
  __syncthreads();
  float o = 0.f;
  for (int r = 0; r < 16; ++r) o += w2[tid*16 + r]*(hA[r] + hM[r]);
  ca[b*128 + tid] = 1.f/(1.f + __expf(-o));
}

// ---------------- K8: final bn affine from per-plane stats + ca ----------------
__global__ void k8_affineF(const float4* __restrict__ planeStats, const float* __restrict__ ca,
    const float* __restrict__ rgb_cw, const float* __restrict__ rgb_bg, const float* __restrict__ rgb_bb,
    const float* __restrict__ fre_cw, const float* __restrict__ fre_bg, const float* __restrict__ fre_bb,
    float* __restrict__ ABF)
{
  int t = threadIdx.x;
  if (t >= 128) return;
  int z = t >> 6, c = t & 63;
  float S = 0.f, Q = 0.f;
  for (int b = 0; b < 32; ++b){
    float4 ps = planeStats[b*64 + c];
    float sc = ca[b*128 + t];
    float sp = z ? ps.z : ps.x;
    float qp = z ? ps.w : ps.y;
    S += sc*sp; Q += sc*sc*qp;
  }
  const float n = 401408.f;
  float m = S/n, v = Q/n - m*m;
  float cw = z ? fre_cw[c] : rgb_cw[c];
  float g  = z ? fre_bg[c] : rgb_bg[c];
  float bb = z ? fre_bb[c] : rgb_bb[c];
  float rs = rsqrtf(cw*cw*v + EPSV);
  ABF[z*128 + c]      = cw*rs*g;
  ABF[z*128 + 64 + c] = -cw*m*rs*g + bb;
}

// ---------------- K9: out = y*(1 + A*ca) + B (bf16 y in, fp32 out) ----------------
__global__ __launch_bounds__(256) void k9_out(
    const unsigned short* __restrict__ ybf, const unsigned short* __restrict__ ybl,
    const float* __restrict__ ca, const float* __restrict__ ABF,
    float* __restrict__ out)
{
  const int c = blockIdx.x, b = blockIdx.y, z = blockIdx.z;
  const size_t plane = ((size_t)b*64 + c)*PP;
  const unsigned short* y = z ? ybl : ybf;
  float* o = out + (z ? NE : 0) + plane;
  const float sc = ca[b*128 + z*64 + c];
  const float A = ABF[z*128 + c], Bv = ABF[z*128 + 64 + c];
  const float mul = 1.f + A*sc;
  for (int i8 = threadIdx.x; i8 < 1568; i8 += 256){
    short8v yv = *(const short8v*)(y + plane + (size_t)i8*8);
    float4 o0, o1;
    o0.x = bf2f((unsigned short)yv[0])*mul + Bv;
    o0.y = bf2f((unsigned short)yv[1])*mul + Bv;
    o0.z = bf2f((unsigned short)yv[2])*mul + Bv;
    o0.w = bf2f((unsigned short)yv[3])*mul + Bv;
    o1.x = bf2f((unsigned short)yv[4])*mul + Bv;
    o1.y = bf2f((unsigned short)yv[5])*mul + Bv;
    o1.z = bf2f((unsigned short)yv[6])*mul + Bv;
    o1.w = bf2f((unsigned short)yv[7])*mul + Bv;
    *(float4*)(&o[(size_t)i8*8])     = o0;
    *(float4*)(&o[(size_t)i8*8 + 4]) = o1;
  }
}

extern "C" void kernel_launch(void* const* d_in, const int* in_sizes, int n_in,
                              void* d_out, int out_size, void* d_ws, size_t ws_size,
                              hipStream_t stream)
{
  (void)in_sizes; (void)n_in; (void)out_size; (void)ws_size;
  const float* rgb      = (const float*)d_in[0];
  const float* fre      = (const float*)d_in[1];
  const float* wq_fad   = (const float*)d_in[2];
  const float* bq_fad   = (const float*)d_in[3];
  const float* wq_lfs   = (const float*)d_in[4];
  const float* bq_lfs   = (const float*)d_in[5];
  const float* wk_fad   = (const float*)d_in[6];
  const float* bk_fad   = (const float*)d_in[7];
  const float* wk_lfs   = (const float*)d_in[8];
  const float* bk_lfs   = (const float*)d_in[9];
  const float* fad_gamma= (const float*)d_in[10];
  const float* lfs_gamma= (const float*)d_in[11];
  const float* fad_cw   = (const float*)d_in[12];
  const float* fad_bg   = (const float*)d_in[14];
  const float* fad_bb   = (const float*)d_in[15];
  const float* lfs_cw   = (const float*)d_in[16];
  const float* lfs_bg   = (const float*)d_in[18];
  const float* lfs_bb   = (const float*)d_in[19];
  const float* lin1_w   = (const float*)d_in[20];
  const float* lin2_w   = (const float*)d_in[21];
  const float* mlp_w1   = (const float*)d_in[22];
  const float* mlp_w2   = (const float*)d_in[23];
  const float* rgb_cw   = (const float*)d_in[24];
  const float* rgb_bg   = (const float*)d_in[26];
  const float* rgb_bb   = (const float*)d_in[27];
  const float* fre_cw   = (const float*)d_in[28];
  const float* fre_bg   = (const float*)d_in[30];
  const float* fre_bb   = (const float*)d_in[31];

  char* ws = (char*)d_ws;
  unsigned short* qF = (unsigned short*)(ws);          // becomes attn after k2
  unsigned short* qL = (unsigned short*)(ws + 2*NE);
  unsigned short* kF = (unsigned short*)(ws + 4*NE);   // becomes y_fad (bf16) after k4
  unsigned short* kL = (unsigned short*)(ws + 6*NE);   // becomes y_lfs (bf16) after k4
  float* sbase = (float*)(ws + 8*NE);
  float* stats      = sbase;               // [0..255]   bn1 atomics (memset)
  float* AB1        = sbase + 256;
  float* avgstat    = sbase + 512;
  float* maxstat    = sbase + 12800;
  float* ca         = sbase + 25088;
  float* ABF        = sbase + 29184;
  float4* planeStats= (float4*)(sbase + 29440);

  hipMemsetAsync(stats, 0, 256*sizeof(float), stream);

  k1_conv<<<dim3(49,32,2), dim3(256), 0, stream>>>(rgb, fre,
      wq_fad, bq_fad, wk_fad, bk_fad, wq_lfs, bq_lfs, wk_lfs, bk_lfs,
      qF, kF, qL, kL);
  k2_attn<<<dim3(2048), dim3(448), 0, stream>>>(qF, qL, kF, kL,
      rgb, fre, fad_gamma, lfs_gamma, stats);
  k3_affine1<<<dim3(1), dim3(64), 0, stream>>>(stats,
      fad_cw, fad_bg, fad_bb, lfs_cw, lfs_bg, lfs_bb, AB1);
  k4_fuse<<<dim3(2048), dim3(512), 0, stream>>>((const unsigned short*)qF,
      rgb, fre, AB1, fad_gamma, lfs_gamma, kF, kL, avgstat, maxstat, planeStats);
  k6_mlp<<<dim3(32), dim3(128), 0, stream>>>(avgstat, maxstat,
      lin1_w, lin2_w, mlp_w1, mlp_w2, ca);
  k8_affineF<<<dim3(1), dim3(128), 0, stream>>>(planeStats, ca,
      rgb_cw, rgb_bg, rgb_bb, fre_cw, fre_bg, fre_bb, ABF);
  k9_out<<<dim3(64,32,2), dim3(256), 0, stream>>>(kF, kL, ca, ABF,
      (float*)d_out);
}

// Round 4
// 475.893 us; speedup vs baseline: 2.0646x; 1.0028x over previous
//
#include <hip/hip_runtime.h>
#include <hip/hip_bf16.h>
#include <stdint.h>

#define NE 25690112ull   // 32*64*112*112
#define PP 12544         // 112*112
#define SS 112
#define EPSV 1e-5f

typedef __attribute__((ext_vector_type(8))) short short8v;
typedef __attribute__((ext_vector_type(4))) float float4v;

__device__ __forceinline__ unsigned short f2bf(float x){
  union { float f; uint32_t u; } v; v.f = x;
  uint32_t r = (v.u + 0x7fffu + ((v.u >> 16) & 1u)) >> 16;
  return (unsigned short)r;
}
__device__ __forceinline__ float bf2f(unsigned short u){ return __uint_as_float(((uint32_t)u) << 16); }

// ---------------- K1: conv1x1 via MFMA with LDS-transposed staging ----------------
// Per (b,z): stage X tile [256 p][64 c] as bf16 in LDS (XOR-swizzled, transposed),
// emit bf16 X copy to global (rgbb/freb) for downstream kernels, then
// D[p][o] = X^T · W^T via mfma_16x16x32_bf16, weights held in registers.
__global__ __launch_bounds__(256) void k1_conv(
    const float* __restrict__ rgb, const float* __restrict__ fre,
    const float* __restrict__ wq_fad, const float* __restrict__ bq_fad,
    const float* __restrict__ wk_fad, const float* __restrict__ bk_fad,
    const float* __restrict__ wq_lfs, const float* __restrict__ bq_lfs,
    const float* __restrict__ wk_lfs, const float* __restrict__ bk_lfs,
    unsigned short* __restrict__ qF, unsigned short* __restrict__ kF,
    unsigned short* __restrict__ qL, unsigned short* __restrict__ kL,
    unsigned short* __restrict__ rgbb, unsigned short* __restrict__ freb)
{
  const int bx = blockIdx.x, b = blockIdx.y, z = blockIdx.z;
  const float* X  = z ? fre : rgb;
  const float* Wq = z ? wq_lfs : wq_fad;
  const float* Bq = z ? bq_lfs : bq_fad;
  const float* Wk = z ? wk_lfs : wk_fad;
  const float* Bk = z ? bk_lfs : bk_fad;
  unsigned short* Oq = z ? qL : qF;
  unsigned short* Ok = z ? kL : kF;
  unsigned short* Xb = z ? freb : rgbb;

  __shared__ __align__(16) unsigned short xs[256 * 64];  // [p][c] bf16, swizzled, 32 KB

  const int tid = threadIdx.x, lane = tid & 63, w = tid >> 6;
  const int lc = lane & 15, l4 = lane >> 4;

  // Weight B-frags: lane holds B[k=c][col=o=lc] = W[o=ot*16+lc][c=ks*32+l4*8+j]
  short8v wqf[4][2], wkf[4][2];
  float bq[4], bk[4];
  #pragma unroll
  for (int ot = 0; ot < 4; ++ot){
    bq[ot] = Bq[ot*16 + lc];
    bk[ot] = Bk[ot*16 + lc];
    #pragma unroll
    for (int ks = 0; ks < 2; ++ks){
      const int base = (ot*16 + lc)*64 + ks*32 + l4*8;
      const float4 q0 = *(const float4*)(Wq + base);
      const float4 q1 = *(const float4*)(Wq + base + 4);
      const float4 k0 = *(const float4*)(Wk + base);
      const float4 k1 = *(const float4*)(Wk + base + 4);
      short8v vq, vk;
      vq[0]=(short)f2bf(q0.x); vq[1]=(short)f2bf(q0.y); vq[2]=(short)f2bf(q0.z); vq[3]=(short)f2bf(q0.w);
      vq[4]=(short)f2bf(q1.x); vq[5]=(short)f2bf(q1.y); vq[6]=(short)f2bf(q1.z); vq[7]=(short)f2bf(q1.w);
      vk[0]=(short)f2bf(k0.x); vk[1]=(short)f2bf(k0.y); vk[2]=(short)f2bf(k0.z); vk[3]=(short)f2bf(k0.w);
      vk[4]=(short)f2bf(k1.x); vk[5]=(short)f2bf(k1.y); vk[6]=(short)f2bf(k1.z); vk[7]=(short)f2bf(k1.w);
      wqf[ot][ks] = vq; wkf[ot][ks] = vk;
    }
  }

  // ---- stage: 256 p x 64 c, wide coalesced loads, 4x4 micro-transpose into LDS ----
  const int p0 = bx*256;
  const size_t xbase = (size_t)b * 64 * PP;
  const int c0 = (tid & 15) * 4;
  const int pq = (tid >> 4) * 4;           // = w*16 + l4*4
  #pragma unroll
  for (int itp = 0; itp < 4; ++itp){
    const int p = itp*64 + pq;             // relative p of this thread's 4-row quad
    float4 xr[4];
    #pragma unroll
    for (int k = 0; k < 4; ++k)
      xr[k] = *(const float4*)(X + xbase + (size_t)(c0+k)*PP + p0 + p);
    // global bf16 copy (same [c][p] layout)
    #pragma unroll
    for (int k = 0; k < 4; ++k){
      ushort4 s;
      s.x = f2bf(xr[k].x); s.y = f2bf(xr[k].y); s.z = f2bf(xr[k].z); s.w = f2bf(xr[k].w);
      *(ushort4*)(Xb + xbase + (size_t)(c0+k)*PP + p0 + p) = s;
    }
    // LDS transposed: row p+j gets c0..c0+3
    float vals[4][4];
    #pragma unroll
    for (int k = 0; k < 4; ++k){ vals[k][0]=xr[k].x; vals[k][1]=xr[k].y; vals[k][2]=xr[k].z; vals[k][3]=xr[k].w; }
    #pragma unroll
    for (int j = 0; j < 4; ++j){
      ushort4 t;
      t.x = f2bf(vals[0][j]); t.y = f2bf(vals[1][j]); t.z = f2bf(vals[2][j]); t.w = f2bf(vals[3][j]);
      uint32_t byteS = (uint32_t)((p+j)*128 + c0*2) ^ (uint32_t)(((p+j) & 7) << 4);
      *(ushort4*)((char*)xs + byteS) = t;
    }
  }
  __syncthreads();

  // ---- compute: 4 tiles of 16 p-rows per wave ----
  #pragma unroll
  for (int t = 0; t < 4; ++t){
    const int pt = (t*4 + w)*16;
    const int row = pt + lc;
    const uint32_t rbase = (uint32_t)(row*128) ;
    const uint32_t sw = (uint32_t)((row & 7) << 4);
    short8v a0 = *(const short8v*)((const char*)xs + ((rbase + l4*16) ^ sw));
    short8v a1 = *(const short8v*)((const char*)xs + ((rbase + 64 + l4*16) ^ sw));

    float4v aq[4], ak[4];
    #pragma unroll
    for (int ot = 0; ot < 4; ++ot){
      aq[ot] = (float4v){bq[ot], bq[ot], bq[ot], bq[ot]};
      ak[ot] = (float4v){bk[ot], bk[ot], bk[ot], bk[ot]};
    }
    #pragma unroll
    for (int ot = 0; ot < 4; ++ot){
      aq[ot] = __builtin_amdgcn_mfma_f32_16x16x32_bf16(a0, wqf[ot][0], aq[ot], 0, 0, 0);
      aq[ot] = __builtin_amdgcn_mfma_f32_16x16x32_bf16(a1, wqf[ot][1], aq[ot], 0, 0, 0);
      ak[ot] = __builtin_amdgcn_mfma_f32_16x16x32_bf16(a0, wkf[ot][0], ak[ot], 0, 0, 0);
      ak[ot] = __builtin_amdgcn_mfma_f32_16x16x32_bf16(a1, wkf[ot][1], ak[ot], 0, 0, 0);
    }
    // D: lane holds o=ot*16+lc, p = p0 + pt + l4*4 + reg
    #pragma unroll
    for (int ot = 0; ot < 4; ++ot){
      const size_t off = ((size_t)b*64 + ot*16 + lc)*PP + p0 + pt + l4*4;
      ushort4 sq, sk;
      sq.x = f2bf(aq[ot][0]); sq.y = f2bf(aq[ot][1]); sq.z = f2bf(aq[ot][2]); sq.w = f2bf(aq[ot][3]);
      sk.x = f2bf(ak[ot][0]); sk.y = f2bf(ak[ot][1]); sk.z = f2bf(ak[ot][2]); sk.w = f2bf(ak[ot][3]);
      *(ushort4*)(Oq + off) = sq;
      *(ushort4*)(Ok + off) = sk;
    }
  }
}

// ---------------- K2: MFMA attention (stats now read bf16 x-copies) ----------------
__global__ __launch_bounds__(448) void k2_attn(
    unsigned short* __restrict__ qF, const unsigned short* __restrict__ qL,
    const unsigned short* __restrict__ kF, const unsigned short* __restrict__ kL,
    const unsigned short* __restrict__ rgbb, const unsigned short* __restrict__ freb,
    const float* __restrict__ fad_gamma, const float* __restrict__ lfs_gamma,
    float* __restrict__ stats)
{
  const int bc = blockIdx.x, c = bc & 63;
  const size_t plane = (size_t)bc * PP;
  __shared__ __align__(16) unsigned short ksF[112][128];
  __shared__ __align__(16) unsigned short ksL[112][128];
  const int tid = threadIdx.x, lane = tid & 63, w = tid >> 6;
  const int l4 = lane >> 4, lc = lane & 15;

  const uint32_t* kFu = (const uint32_t*)kF + plane/2;
  const uint32_t* kLu = (const uint32_t*)kL + plane/2;
  for (int i = tid; i < 7168; i += 448){
    int row = i >> 6, wd = i & 63;
    uint32_t vF = (wd < 56) ? kFu[row*56 + wd] : 0u;
    uint32_t vL = (wd < 56) ? kLu[row*56 + wd] : 0u;
    uint32_t byteS = (uint32_t)((row << 8) | (wd << 2)) ^ (uint32_t)((row & 7) << 4);
    *(uint32_t*)((char*)&ksF[0][0] + byteS) = vF;
    *(uint32_t*)((char*)&ksL[0][0] + byteS) = vL;
  }
  __syncthreads();

  float4v acc[7];
  #pragma unroll
  for (int ct = 0; ct < 7; ++ct) acc[ct] = (float4v)0.f;

  const unsigned short* qFp = qF + plane;
  const unsigned short* qLp = qL + plane;
  const int qrow = w*16 + lc;
  #pragma unroll
  for (int ks = 0; ks < 4; ++ks){
    short8v aF = (short8v)(short)0, aL = (short8v)(short)0;
    const int joff = ks*32 + l4*8;
    if ((ks < 3) || (l4 < 2)){
      aF = *(const short8v*)(qFp + qrow*SS + joff);
      aL = *(const short8v*)(qLp + qrow*SS + joff);
    }
    #pragma unroll
    for (int ct = 0; ct < 7; ++ct){
      uint32_t byteS = (uint32_t)((ct*16 + lc)*256 + ks*64 + l4*16) ^ (uint32_t)((lc & 7) << 4);
      short8v bF = *(const short8v*)((const char*)&ksF[0][0] + byteS);
      short8v bL = *(const short8v*)((const char*)&ksL[0][0] + byteS);
      acc[ct] = __builtin_amdgcn_mfma_f32_16x16x32_bf16(aF, bF, acc[ct], 0, 0, 0);
      acc[ct] = __builtin_amdgcn_mfma_f32_16x16x32_bf16(aL, bL, acc[ct], 0, 0, 0);
    }
  }

  const float sF = 2.f/(1.f + __expf(-fad_gamma[0])) - 1.f;
  const float sL = 2.f/(1.f + __expf(-lfs_gamma[0])) - 1.f;
  float ls1 = 0.f, lq1 = 0.f, ls2 = 0.f, lq2 = 0.f;
  unsigned short* attnP = qF + plane;

  #pragma unroll
  for (int r = 0; r < 4; ++r){
    const int i = w*16 + l4*4 + r;
    float v[7];
    #pragma unroll
    for (int ct = 0; ct < 7; ++ct) v[ct] = acc[ct][r];
    float m = fmaxf(fmaxf(fmaxf(v[0],v[1]),fmaxf(v[2],v[3])), fmaxf(fmaxf(v[4],v[5]),v[6]));
    #pragma unroll
    for (int off = 8; off; off >>= 1) m = fmaxf(m, __shfl_xor(m, off, 64));
    float e[7]; float s = 0.f;
    #pragma unroll
    for (int ct = 0; ct < 7; ++ct){ e[ct] = __expf(v[ct] - m); s += e[ct]; }
    #pragma unroll
    for (int off = 8; off; off >>= 1) s += __shfl_xor(s, off, 64);
    const float inv = 1.f / s;
    const size_t rb = plane + (size_t)i * SS;
    #pragma unroll
    for (int ct = 0; ct < 7; ++ct){
      const int col = ct*16 + lc;
      unsigned short ab = f2bf(e[ct] * inv);
      attnP[(size_t)i*SS + col] = ab;
      float a  = bf2f(ab);
      float frv = bf2f(freb[rb + col]), rgv = bf2f(rgbb[rb + col]);
      float v1 = frv * a * sL, v2 = rgv * a * sF;
      ls1 += v1; lq1 += v1*v1; ls2 += v2; lq2 += v2*v2;
    }
  }
  #pragma unroll
  for (int off = 32; off; off >>= 1){
    ls1 += __shfl_xor(ls1, off, 64);
    lq1 += __shfl_xor(lq1, off, 64);
    ls2 += __shfl_xor(ls2, off, 64);
    lq2 += __shfl_xor(lq2, off, 64);
  }
  if (lane == 0){
    atomicAdd(&stats[c],       ls1);
    atomicAdd(&stats[64 + c],  lq1);
    atomicAdd(&stats[128 + c], ls2);
    atomicAdd(&stats[192 + c], lq2);
  }
}

// ---------------- K3: bn1 stats -> affine ----------------
__global__ void k3_affine1(const float* __restrict__ stats,
    const float* __restrict__ fad_cw, const float* __restrict__ fad_bg, const float* __restrict__ fad_bb,
    const float* __restrict__ lfs_cw, const float* __restrict__ lfs_bg, const float* __restrict__ lfs_bb,
    float* __restrict__ AB)
{
  int c = threadIdx.x;
  if (c >= 64) return;
  const float n = 401408.f;
  {
    float m1 = stats[c]/n, v1 = stats[64+c]/n - (stats[c]/n)*(stats[c]/n);
    float cw = fad_cw[c], g = fad_bg[c];
    float rs = rsqrtf(cw*cw*v1 + EPSV);
    AB[c]      = cw*rs*g;
    AB[64 + c] = -cw*m1*rs*g + fad_bb[c];
  }
  {
    float m2 = stats[128+c]/n, v2 = stats[192+c]/n - (stats[128+c]/n)*(stats[128+c]/n);
    float cw = lfs_cw[c], g = lfs_bg[c];
    float rs = rsqrtf(cw*cw*v2 + EPSV);
    AB[128 + c] = cw*rs*g;
    AB[192 + c] = -cw*m2*rs*g + lfs_bb[c];
  }
}

// ---------------- K4: fused y (bf16 out) + pooling + per-plane stats ----------------
__global__ __launch_bounds__(512) void k4_fuse(
    const unsigned short* __restrict__ attn,
    const unsigned short* __restrict__ rgbb, const unsigned short* __restrict__ freb,
    const float* __restrict__ AB1,
    const float* __restrict__ fad_gamma, const float* __restrict__ lfs_gamma,
    unsigned short* __restrict__ ybf, unsigned short* __restrict__ ybl,
    float* __restrict__ avgstat, float* __restrict__ maxstat,
    float4* __restrict__ planeStats)
{
  const int bc = blockIdx.x, b = bc >> 6, c = bc & 63;
  const size_t plane = (size_t)bc * PP;
  __shared__ unsigned short ys[2][112][113];
  __shared__ float redA[8][4];
  __shared__ float redS[8], redM[8];
  const int tid = threadIdx.x, lane = tid & 63, w = tid >> 6;
  const float sF = 2.f/(1.f + __expf(-fad_gamma[0])) - 1.f;
  const float sL = 2.f/(1.f + __expf(-lfs_gamma[0])) - 1.f;
  const float A1 = AB1[c], B1 = AB1[64+c], A2 = AB1[128+c], B2 = AB1[192+c];
  float s0 = 0.f, q0 = 0.f, s1 = 0.f, q1 = 0.f;

  for (int i4 = tid; i4 < 3136; i4 += 512){
    ushort4 av = *(const ushort4*)(attn + plane + (size_t)i4*4);
    ushort4 rg = *(const ushort4*)(rgbb + plane + (size_t)i4*4);
    ushort4 fr = *(const ushort4*)(freb + plane + (size_t)i4*4);
    float aa[4] = {bf2f(av.x), bf2f(av.y), bf2f(av.z), bf2f(av.w)};
    float rr[4] = {bf2f(rg.x), bf2f(rg.y), bf2f(rg.z), bf2f(rg.w)};
    float ff[4] = {bf2f(fr.x), bf2f(fr.y), bf2f(fr.z), bf2f(fr.w)};
    float y0[4], y1[4];
    ushort4 o0, o1;
    unsigned short* p0 = &o0.x; unsigned short* p1 = &o1.x;
    #pragma unroll
    for (int j = 0; j < 4; ++j){
      float t1 = ff[j]*aa[j]*sL;
      float t2 = rr[j]*aa[j]*sF;
      y0[j] = rr[j] + A1*t1 + B1;
      y1[j] = ff[j] + A2*t2 + B2;
      s0 += y0[j]; q0 += y0[j]*y0[j];
      s1 += y1[j]; q1 += y1[j]*y1[j];
      p0[j] = f2bf(y0[j]);
      p1[j] = f2bf(y1[j]);
    }
    *(ushort4*)(ybf + plane + (size_t)i4*4) = o0;
    *(ushort4*)(ybl + plane + (size_t)i4*4) = o1;
    int r = i4 / 28, c0 = (i4 % 28) * 4;
    #pragma unroll
    for (int j = 0; j < 4; ++j){
      ys[0][r][c0+j] = p0[j];
      ys[1][r][c0+j] = p1[j];
    }
  }
  #pragma unroll
  for (int off = 32; off; off >>= 1){
    s0 += __shfl_xor(s0, off, 64); q0 += __shfl_xor(q0, off, 64);
    s1 += __shfl_xor(s1, off, 64); q1 += __shfl_xor(q1, off, 64);
  }
  if (lane == 0){ redA[w][0] = s0; redA[w][1] = q0; redA[w][2] = s1; redA[w][3] = q1; }
  __syncthreads();
  if (tid == 0){
    float a0=0,a1=0,a2=0,a3=0;
    for (int i = 0; i < 8; ++i){ a0+=redA[i][0]; a1+=redA[i][1]; a2+=redA[i][2]; a3+=redA[i][3]; }
    float4 ps = {a0,a1,a2,a3};
    planeStats[bc] = ps;
  }
  __syncthreads();

  const int kk[3] = {3,5,7};
  const int gg[3] = {37,22,16};
  for (int pl = 0; pl < 2; ++pl){
    const int cc = pl*64 + c;
    for (int ki = 0; ki < 3; ++ki){
      const int k = kk[ki], g = gg[ki];
      float sumAll = 0.f, mx = -3.0e38f;
      for (int win = tid; win < g*g; win += 512){
        int wy = win / g, wx = win % g;
        float s = 0.f;
        for (int dy = 0; dy < k; ++dy)
          for (int dx = 0; dx < k; ++dx)
            s += bf2f(ys[pl][wy*k+dy][wx*k+dx]);
        sumAll += s; mx = fmaxf(mx, s);
      }
      #pragma unroll
      for (int off = 32; off; off >>= 1){
        sumAll += __shfl_xor(sumAll, off, 64);
        mx = fmaxf(mx, __shfl_xor(mx, off, 64));
      }
      if (lane == 0){ redS[w] = sumAll; redM[w] = mx; }
      __syncthreads();
      if (tid == 0){
        float st = 0.f, mt = -3.0e38f;
        for (int i = 0; i < 8; ++i){ st += redS[i]; mt = fmaxf(mt, redM[i]); }
        int idx = (b*128 + cc)*3 + ki;
        avgstat[idx] = st / (float)(k*k*g*g);
        maxstat[idx] = mt / (float)(k*k);
      }
      __syncthreads();
    }
  }
}

// ---------------- K6: channel-attention MLP ----------------
__global__ void k6_mlp(const float* __restrict__ avgstat, const float* __restrict__ maxstat,
    const float* __restrict__ lin1, const float* __restrict__ lin2,
    const float* __restrict__ w1, const float* __restrict__ w2,
    float* __restrict__ ca)
{
  const int b = blockIdx.x, tid = threadIdx.x; // 128 threads
  __shared__ float sa[128], sm[128], hA[16], hM[16];
  int idx = (b*128 + tid)*3;
  sa[tid] = avgstat[idx]*lin1[0] + avgstat[idx+1]*lin1[1] + avgstat[idx+2]*lin1[2];
  sm[tid] = maxstat[idx]*lin2[0] + maxstat[idx+1]*lin2[1] + maxstat[idx+2]*lin2[2];
  __syncthreads();
  if (tid < 16){
    float ha = 0.f, hm = 0.f;
    for (int c2 = 0; c2 < 128; ++c2){
      ha += w1[tid*128 + c2]*sa[c2];
      hm += w1[tid*128 + c2]*sm[c2];
    }
    hA[tid] = fmaxf(ha, 0.f); hM[tid] = fmaxf(hm, 0.f);
  }
  __syncthreads();
  float o = 0.f;
  for (int r = 0; r < 16; ++r) o += w2[tid*16 + r]*(hA[r] + hM[r]);
  ca[b*128 + tid] = 1.f/(1.f + __expf(-o));
}

// ---------------- K8: final bn affine from per-plane stats + ca ----------------
__global__ void k8_affineF(const float4* __restrict__ planeStats, const float* __restrict__ ca,
    const float* __restrict__ rgb_cw, const float* __restrict__ rgb_bg, const float* __restrict__ rgb_bb,
    const float* __restrict__ fre_cw, const float* __restrict__ fre_bg, const float* __restrict__ fre_bb,
    float* __restrict__ ABF)
{
  int t = threadIdx.x;
  if (t >= 128) return;
  int z = t >> 6, c = t & 63;
  float S = 0.f, Q = 0.f;
  for (int b = 0; b < 32; ++b){
    float4 ps = planeStats[b*64 + c];
    float sc = ca[b*128 + t];
    float sp = z ? ps.z : ps.x;
    float qp = z ? ps.w : ps.y;
    S += sc*sp; Q += sc*sc*qp;
  }
  const float n = 401408.f;
  float m = S/n, v = Q/n - m*m;
  float cw = z ? fre_cw[c] : rgb_cw[c];
  float g  = z ? fre_bg[c] : rgb_bg[c];
  float bb = z ? fre_bb[c] : rgb_bb[c];
  float rs = rsqrtf(cw*cw*v + EPSV);
  ABF[z*128 + c]      = cw*rs*g;
  ABF[z*128 + 64 + c] = -cw*m*rs*g + bb;
}

// ---------------- K9: out = y*(1 + A*ca) + B (bf16 y in, fp32 out) ----------------
__global__ __launch_bounds__(256) void k9_out(
    const unsigned short* __restrict__ ybf, const unsigned short* __restrict__ ybl,
    const float* __restrict__ ca, const float* __restrict__ ABF,
    float* __restrict__ out)
{
  const int c = blockIdx.x, b = blockIdx.y, z = blockIdx.z;
  const size_t plane = ((size_t)b*64 + c)*PP;
  const unsigned short* y = z ? ybl : ybf;
  float* o = out + (z ? NE : 0) + plane;
  const float sc = ca[b*128 + z*64 + c];
  const float A = ABF[z*128 + c], Bv = ABF[z*128 + 64 + c];
  const float mul = 1.f + A*sc;
  for (int i8 = threadIdx.x; i8 < 1568; i8 += 256){
    short8v yv = *(const short8v*)(y + plane + (size_t)i8*8);
    float4 o0, o1;
    o0.x = bf2f((unsigned short)yv[0])*mul + Bv;
    o0.y = bf2f((unsigned short)yv[1])*mul + Bv;
    o0.z = bf2f((unsigned short)yv[2])*mul + Bv;
    o0.w = bf2f((unsigned short)yv[3])*mul + Bv;
    o1.x = bf2f((unsigned short)yv[4])*mul + Bv;
    o1.y = bf2f((unsigned short)yv[5])*mul + Bv;
    o1.z = bf2f((unsigned short)yv[6])*mul + Bv;
    o1.w = bf2f((unsigned short)yv[7])*mul + Bv;
    *(float4*)(&o[(size_t)i8*8])     = o0;
    *(float4*)(&o[(size_t)i8*8 + 4]) = o1;
  }
}

extern "C" void kernel_launch(void* const* d_in, const int* in_sizes, int n_in,
                              void* d_out, int out_size, void* d_ws, size_t ws_size,
                              hipStream_t stream)
{
  (void)in_sizes; (void)n_in; (void)out_size; (void)ws_size;
  const float* rgb      = (const float*)d_in[0];
  const float* fre      = (const float*)d_in[1];
  const float* wq_fad   = (const float*)d_in[2];
  const float* bq_fad   = (const float*)d_in[3];
  const float* wq_lfs   = (const float*)d_in[4];
  const float* bq_lfs   = (const float*)d_in[5];
  const float* wk_fad   = (const float*)d_in[6];
  const float* bk_fad   = (const float*)d_in[7];
  const float* wk_lfs   = (const float*)d_in[8];
  const float* bk_lfs   = (const float*)d_in[9];
  const float* fad_gamma= (const float*)d_in[10];
  const float* lfs_gamma= (const float*)d_in[11];
  const float* fad_cw   = (const float*)d_in[12];
  const float* fad_bg   = (const float*)d_in[14];
  const float* fad_bb   = (const float*)d_in[15];
  const float* lfs_cw   = (const float*)d_in[16];
  const float* lfs_bg   = (const float*)d_in[18];
  const float* lfs_bb   = (const float*)d_in[19];
  const float* lin1_w   = (const float*)d_in[20];
  const float* lin2_w   = (const float*)d_in[21];
  const float* mlp_w1   = (const float*)d_in[22];
  const float* mlp_w2   = (const float*)d_in[23];
  const float* rgb_cw   = (const float*)d_in[24];
  const float* rgb_bg   = (const float*)d_in[26];
  const float* rgb_bb   = (const float*)d_in[27];
  const float* fre_cw   = (const float*)d_in[28];
  const float* fre_bg   = (const float*)d_in[30];
  const float* fre_bb   = (const float*)d_in[31];

  char* ws = (char*)d_ws;
  unsigned short* qF = (unsigned short*)(ws);          // becomes attn after k2
  unsigned short* qL = (unsigned short*)(ws + 2*NE);
  unsigned short* kF = (unsigned short*)(ws + 4*NE);   // becomes y_fad (bf16) after k4
  unsigned short* kL = (unsigned short*)(ws + 6*NE);   // becomes y_lfs (bf16) after k4
  float* sbase = (float*)(ws + 8*NE);
  float* stats      = sbase;               // [0..255]   bn1 atomics (memset)
  float* AB1        = sbase + 256;
  float* avgstat    = sbase + 512;
  float* maxstat    = sbase + 12800;
  float* ca         = sbase + 25088;
  float* ABF        = sbase + 29184;
  float4* planeStats= (float4*)(sbase + 29440);
  // bf16 copies of rgb/fre live in the FIRST HALF of d_out (4*NE bytes of 8*NE);
  // consumed by k2/k4, then k9 overwrites all of d_out. Rewritten every call.
  unsigned short* rgbb = (unsigned short*)d_out;
  unsigned short* freb = (unsigned short*)d_out + NE;

  hipMemsetAsync(stats, 0, 256*sizeof(float), stream);

  k1_conv<<<dim3(49,32,2), dim3(256), 0, stream>>>(rgb, fre,
      wq_fad, bq_fad, wk_fad, bk_fad, wq_lfs, bq_lfs, wk_lfs, bk_lfs,
      qF, kF, qL, kL, rgbb, freb);
  k2_attn<<<dim3(2048), dim3(448), 0, stream>>>(qF, qL, kF, kL,
      rgbb, freb, fad_gamma, lfs_gamma, stats);
  k3_affine1<<<dim3(1), dim3(64), 0, stream>>>(stats,
      fad_cw, fad_bg, fad_bb, lfs_cw, lfs_bg, lfs_bb, AB1);
  k4_fuse<<<dim3(2048), dim3(512), 0, stream>>>((const unsigned short*)qF,
      rgbb, freb, AB1, fad_gamma, lfs_gamma, kF, kL, avgstat, maxstat, planeStats);
  k6_mlp<<<dim3(32), dim3(128), 0, stream>>>(avgstat, maxstat,
      lin1_w, lin2_w, mlp_w1, mlp_w2, ca);
  k8_affineF<<<dim3(1), dim3(128), 0, stream>>>(planeStats, ca,
      rgb_cw, rgb_bg, rgb_bb, fre_cw, fre_bg, fre_bb, ABF);
  k9_out<<<dim3(64,32,2), dim3(256), 0, stream>>>(kF, kL, ca, ABF,
      (float*)d_out);
}

// Round 5
// 446.328 us; speedup vs baseline: 2.2013x; 1.0662x over previous
//
#include <hip/hip_runtime.h>
#include <hip/hip_bf16.h>
#include <stdint.h>

#define NE 25690112ull   // 32*64*112*112
#define PP 12544         // 112*112
#define SS 112
#define EPSV 1e-5f

typedef __attribute__((ext_vector_type(8))) short short8v;
typedef __attribute__((ext_vector_type(4))) float float4v;

__device__ __forceinline__ unsigned short f2bf(float x){
  union { float f; uint32_t u; } v; v.f = x;
  uint32_t r = (v.u + 0x7fffu + ((v.u >> 16) & 1u)) >> 16;
  return (unsigned short)r;
}
__device__ __forceinline__ float bf2f(unsigned short u){ return __uint_as_float(((uint32_t)u) << 16); }

// ---------------- K1: conv1x1 via MFMA, LDS-staged IN and OUT ----------------
// Phases: stage X->LDS (transposed bf16, swizzled) + emit bf16 X copy; pre-read
// all A-frags; compute Q, stage D->LDS [o][p], store 256B-coalesced; same for K.
__global__ __launch_bounds__(256) void k1_conv(
    const float* __restrict__ rgb, const float* __restrict__ fre,
    const float* __restrict__ wq_fad, const float* __restrict__ bq_fad,
    const float* __restrict__ wk_fad, const float* __restrict__ bk_fad,
    const float* __restrict__ wq_lfs, const float* __restrict__ bq_lfs,
    const float* __restrict__ wk_lfs, const float* __restrict__ bk_lfs,
    unsigned short* __restrict__ qF, unsigned short* __restrict__ kF,
    unsigned short* __restrict__ qL, unsigned short* __restrict__ kL,
    unsigned short* __restrict__ rgbb, unsigned short* __restrict__ freb)
{
  const int bx = blockIdx.x, b = blockIdx.y, z = blockIdx.z;
  const float* X  = z ? fre : rgb;
  const float* Wq = z ? wq_lfs : wq_fad;
  const float* Bq = z ? bq_lfs : bq_fad;
  const float* Wk = z ? wk_lfs : wk_fad;
  const float* Bk = z ? bk_lfs : bk_fad;
  unsigned short* Oq = z ? qL : qF;
  unsigned short* Ok = z ? kL : kF;
  unsigned short* Xb = z ? freb : rgbb;

  __shared__ __align__(16) unsigned short xs[256 * 64];  // 32 KB, reused in+out

  const int tid = threadIdx.x, lane = tid & 63, w = tid >> 6;
  const int lc = lane & 15, l4 = lane >> 4;

  // ---- Phase A: stage 256p x 64c, wide loads, 4x4 micro-transpose into LDS ----
  const int p0 = bx*256;
  const size_t xbase = (size_t)b * 64 * PP;
  const int c0 = (tid & 15) * 4;
  const int pq = (tid >> 4) * 4;
  #pragma unroll
  for (int itp = 0; itp < 4; ++itp){
    const int p = itp*64 + pq;
    float4 xr[4];
    #pragma unroll
    for (int k = 0; k < 4; ++k)
      xr[k] = *(const float4*)(X + xbase + (size_t)(c0+k)*PP + p0 + p);
    #pragma unroll
    for (int k = 0; k < 4; ++k){
      ushort4 s;
      s.x = f2bf(xr[k].x); s.y = f2bf(xr[k].y); s.z = f2bf(xr[k].z); s.w = f2bf(xr[k].w);
      *(ushort4*)(Xb + xbase + (size_t)(c0+k)*PP + p0 + p) = s;
    }
    float vals[4][4];
    #pragma unroll
    for (int k = 0; k < 4; ++k){ vals[k][0]=xr[k].x; vals[k][1]=xr[k].y; vals[k][2]=xr[k].z; vals[k][3]=xr[k].w; }
    #pragma unroll
    for (int j = 0; j < 4; ++j){
      ushort4 t;
      t.x = f2bf(vals[0][j]); t.y = f2bf(vals[1][j]); t.z = f2bf(vals[2][j]); t.w = f2bf(vals[3][j]);
      uint32_t byteS = (uint32_t)((p+j)*128 + c0*2) ^ (uint32_t)(((p+j) & 7) << 4);
      *(ushort4*)((char*)xs + byteS) = t;
    }
  }
  __syncthreads();

  // ---- Phase B: pre-read ALL A-frags (xs becomes free afterwards) ----
  short8v afr[4][2];
  #pragma unroll
  for (int t = 0; t < 4; ++t){
    const int row = (t*4 + w)*16 + lc;
    const uint32_t rbase = (uint32_t)(row*128);
    const uint32_t sw = (uint32_t)((row & 7) << 4);
    afr[t][0] = *(const short8v*)((const char*)xs + ((rbase + l4*16) ^ sw));
    afr[t][1] = *(const short8v*)((const char*)xs + ((rbase + 64 + l4*16) ^ sw));
  }
  __syncthreads();

  // ---- Phase C/D: per array {Q,K}: compute -> D to LDS [o][256p] -> coalesced store
  #pragma unroll
  for (int arr = 0; arr < 2; ++arr){
    const float* W = arr ? Wk : Wq;
    const float* Bi = arr ? Bk : Bq;
    unsigned short* O = arr ? Ok : Oq;
    // weight B-frags for this array: lane holds W[o=ot*16+lc][c=ks*32+l4*8+j]
    short8v wf[4][2];
    float bias[4];
    #pragma unroll
    for (int ot = 0; ot < 4; ++ot){
      bias[ot] = Bi[ot*16 + lc];
      #pragma unroll
      for (int ks = 0; ks < 2; ++ks){
        const int base = (ot*16 + lc)*64 + ks*32 + l4*8;
        const float4 q0 = *(const float4*)(W + base);
        const float4 q1 = *(const float4*)(W + base + 4);
        short8v v;
        v[0]=(short)f2bf(q0.x); v[1]=(short)f2bf(q0.y); v[2]=(short)f2bf(q0.z); v[3]=(short)f2bf(q0.w);
        v[4]=(short)f2bf(q1.x); v[5]=(short)f2bf(q1.y); v[6]=(short)f2bf(q1.z); v[7]=(short)f2bf(q1.w);
        wf[ot][ks] = v;
      }
    }
    #pragma unroll
    for (int t = 0; t < 4; ++t){
      const int pt = (t*4 + w)*16;
      #pragma unroll
      for (int ot = 0; ot < 4; ++ot){
        float4v acc = (float4v){bias[ot], bias[ot], bias[ot], bias[ot]};
        acc = __builtin_amdgcn_mfma_f32_16x16x32_bf16(afr[t][0], wf[ot][0], acc, 0, 0, 0);
        acc = __builtin_amdgcn_mfma_f32_16x16x32_bf16(afr[t][1], wf[ot][1], acc, 0, 0, 0);
        ushort4 u;
        u.x = f2bf(acc[0]); u.y = f2bf(acc[1]); u.z = f2bf(acc[2]); u.w = f2bf(acc[3]);
        const int o = ot*16 + lc;
        uint32_t byteS = (uint32_t)(o*512 + (pt + l4*4)*2) ^ (uint32_t)((o & 7) << 4);
        *(ushort4*)((char*)xs + byteS) = u;
      }
    }
    __syncthreads();
    // coalesced store: each row o is 512B contiguous (256 p)
    for (int i = tid; i < 2048; i += 256){
      const int o = i >> 5, s = i & 31;
      uint32_t byteS = (uint32_t)(o*512 + s*16) ^ (uint32_t)((o & 7) << 4);
      short8v v = *(const short8v*)((const char*)xs + byteS);
      *(short8v*)(O + ((size_t)b*64 + o)*PP + p0 + s*8) = v;
    }
    __syncthreads();
  }
}

// ---------------- K2: MFMA attention (unchanged) ----------------
__global__ __launch_bounds__(448) void k2_attn(
    unsigned short* __restrict__ qF, const unsigned short* __restrict__ qL,
    const unsigned short* __restrict__ kF, const unsigned short* __restrict__ kL,
    const unsigned short* __restrict__ rgbb, const unsigned short* __restrict__ freb,
    const float* __restrict__ fad_gamma, const float* __restrict__ lfs_gamma,
    float* __restrict__ stats)
{
  const int bc = blockIdx.x, c = bc & 63;
  const size_t plane = (size_t)bc * PP;
  __shared__ __align__(16) unsigned short ksF[112][128];
  __shared__ __align__(16) unsigned short ksL[112][128];
  const int tid = threadIdx.x, lane = tid & 63, w = tid >> 6;
  const int l4 = lane >> 4, lc = lane & 15;

  const uint32_t* kFu = (const uint32_t*)kF + plane/2;
  const uint32_t* kLu = (const uint32_t*)kL + plane/2;
  for (int i = tid; i < 7168; i += 448){
    int row = i >> 6, wd = i & 63;
    uint32_t vF = (wd < 56) ? kFu[row*56 + wd] : 0u;
    uint32_t vL = (wd < 56) ? kLu[row*56 + wd] : 0u;
    uint32_t byteS = (uint32_t)((row << 8) | (wd << 2)) ^ (uint32_t)((row & 7) << 4);
    *(uint32_t*)((char*)&ksF[0][0] + byteS) = vF;
    *(uint32_t*)((char*)&ksL[0][0] + byteS) = vL;
  }
  __syncthreads();

  float4v acc[7];
  #pragma unroll
  for (int ct = 0; ct < 7; ++ct) acc[ct] = (float4v)0.f;

  const unsigned short* qFp = qF + plane;
  const unsigned short* qLp = qL + plane;
  const int qrow = w*16 + lc;
  #pragma unroll
  for (int ks = 0; ks < 4; ++ks){
    short8v aF = (short8v)(short)0, aL = (short8v)(short)0;
    const int joff = ks*32 + l4*8;
    if ((ks < 3) || (l4 < 2)){
      aF = *(const short8v*)(qFp + qrow*SS + joff);
      aL = *(const short8v*)(qLp + qrow*SS + joff);
    }
    #pragma unroll
    for (int ct = 0; ct < 7; ++ct){
      uint32_t byteS = (uint32_t)((ct*16 + lc)*256 + ks*64 + l4*16) ^ (uint32_t)((lc & 7) << 4);
      short8v bF = *(const short8v*)((const char*)&ksF[0][0] + byteS);
      short8v bL = *(const short8v*)((const char*)&ksL[0][0] + byteS);
      acc[ct] = __builtin_amdgcn_mfma_f32_16x16x32_bf16(aF, bF, acc[ct], 0, 0, 0);
      acc[ct] = __builtin_amdgcn_mfma_f32_16x16x32_bf16(aL, bL, acc[ct], 0, 0, 0);
    }
  }

  const float sF = 2.f/(1.f + __expf(-fad_gamma[0])) - 1.f;
  const float sL = 2.f/(1.f + __expf(-lfs_gamma[0])) - 1.f;
  float ls1 = 0.f, lq1 = 0.f, ls2 = 0.f, lq2 = 0.f;
  unsigned short* attnP = qF + plane;

  #pragma unroll
  for (int r = 0; r < 4; ++r){
    const int i = w*16 + l4*4 + r;
    float v[7];
    #pragma unroll
    for (int ct = 0; ct < 7; ++ct) v[ct] = acc[ct][r];
    float m = fmaxf(fmaxf(fmaxf(v[0],v[1]),fmaxf(v[2],v[3])), fmaxf(fmaxf(v[4],v[5]),v[6]));
    #pragma unroll
    for (int off = 8; off; off >>= 1) m = fmaxf(m, __shfl_xor(m, off, 64));
    float e[7]; float s = 0.f;
    #pragma unroll
    for (int ct = 0; ct < 7; ++ct){ e[ct] = __expf(v[ct] - m); s += e[ct]; }
    #pragma unroll
    for (int off = 8; off; off >>= 1) s += __shfl_xor(s, off, 64);
    const float inv = 1.f / s;
    const size_t rb = plane + (size_t)i * SS;
    #pragma unroll
    for (int ct = 0; ct < 7; ++ct){
      const int col = ct*16 + lc;
      unsigned short ab = f2bf(e[ct] * inv);
      attnP[(size_t)i*SS + col] = ab;
      float a  = bf2f(ab);
      float frv = bf2f(freb[rb + col]), rgv = bf2f(rgbb[rb + col]);
      float v1 = frv * a * sL, v2 = rgv * a * sF;
      ls1 += v1; lq1 += v1*v1; ls2 += v2; lq2 += v2*v2;
    }
  }
  #pragma unroll
  for (int off = 32; off; off >>= 1){
    ls1 += __shfl_xor(ls1, off, 64);
    lq1 += __shfl_xor(lq1, off, 64);
    ls2 += __shfl_xor(ls2, off, 64);
    lq2 += __shfl_xor(lq2, off, 64);
  }
  if (lane == 0){
    atomicAdd(&stats[c],       ls1);
    atomicAdd(&stats[64 + c],  lq1);
    atomicAdd(&stats[128 + c], ls2);
    atomicAdd(&stats[192 + c], lq2);
  }
}

// ---------------- K3: bn1 stats -> affine ----------------
__global__ void k3_affine1(const float* __restrict__ stats,
    const float* __restrict__ fad_cw, const float* __restrict__ fad_bg, const float* __restrict__ fad_bb,
    const float* __restrict__ lfs_cw, const float* __restrict__ lfs_bg, const float* __restrict__ lfs_bb,
    float* __restrict__ AB)
{
  int c = threadIdx.x;
  if (c >= 64) return;
  const float n = 401408.f;
  {
    float m1 = stats[c]/n, v1 = stats[64+c]/n - (stats[c]/n)*(stats[c]/n);
    float cw = fad_cw[c], g = fad_bg[c];
    float rs = rsqrtf(cw*cw*v1 + EPSV);
    AB[c]      = cw*rs*g;
    AB[64 + c] = -cw*m1*rs*g + fad_bb[c];
  }
  {
    float m2 = stats[128+c]/n, v2 = stats[192+c]/n - (stats[128+c]/n)*(stats[128+c]/n);
    float cw = lfs_cw[c], g = lfs_bg[c];
    float rs = rsqrtf(cw*cw*v2 + EPSV);
    AB[128 + c] = cw*rs*g;
    AB[192 + c] = -cw*m2*rs*g + lfs_bb[c];
  }
}

// ---------------- K4: fused y (bf16 out) + pooling + per-plane stats ----------------
__global__ __launch_bounds__(512) void k4_fuse(
    const unsigned short* __restrict__ attn,
    const unsigned short* __restrict__ rgbb, const unsigned short* __restrict__ freb,
    const float* __restrict__ AB1,
    const float* __restrict__ fad_gamma, const float* __restrict__ lfs_gamma,
    unsigned short* __restrict__ ybf, unsigned short* __restrict__ ybl,
    float* __restrict__ avgstat, float* __restrict__ maxstat,
    float4* __restrict__ planeStats)
{
  const int bc = blockIdx.x, b = bc >> 6, c = bc & 63;
  const size_t plane = (size_t)bc * PP;
  __shared__ unsigned short ys[2][112][113];
  __shared__ float redA[8][4];
  __shared__ float redS[8], redM[8];
  const int tid = threadIdx.x, lane = tid & 63, w = tid >> 6;
  const float sF = 2.f/(1.f + __expf(-fad_gamma[0])) - 1.f;
  const float sL = 2.f/(1.f + __expf(-lfs_gamma[0])) - 1.f;
  const float A1 = AB1[c], B1 = AB1[64+c], A2 = AB1[128+c], B2 = AB1[192+c];
  float s0 = 0.f, q0 = 0.f, s1 = 0.f, q1 = 0.f;

  for (int i4 = tid; i4 < 3136; i4 += 512){
    ushort4 av = *(const ushort4*)(attn + plane + (size_t)i4*4);
    ushort4 rg = *(const ushort4*)(rgbb + plane + (size_t)i4*4);
    ushort4 fr = *(const ushort4*)(freb + plane + (size_t)i4*4);
    float aa[4] = {bf2f(av.x), bf2f(av.y), bf2f(av.z), bf2f(av.w)};
    float rr[4] = {bf2f(rg.x), bf2f(rg.y), bf2f(rg.z), bf2f(rg.w)};
    float ff[4] = {bf2f(fr.x), bf2f(fr.y), bf2f(fr.z), bf2f(fr.w)};
    float y0[4], y1[4];
    ushort4 o0, o1;
    unsigned short* p0 = &o0.x; unsigned short* p1 = &o1.x;
    #pragma unroll
    for (int j = 0; j < 4; ++j){
      float t1 = ff[j]*aa[j]*sL;
      float t2 = rr[j]*aa[j]*sF;
      y0[j] = rr[j] + A1*t1 + B1;
      y1[j] = ff[j] + A2*t2 + B2;
      s0 += y0[j]; q0 += y0[j]*y0[j];
      s1 += y1[j]; q1 += y1[j]*y1[j];
      p0[j] = f2bf(y0[j]);
      p1[j] = f2bf(y1[j]);
    }
    *(ushort4*)(ybf + plane + (size_t)i4*4) = o0;
    *(ushort4*)(ybl + plane + (size_t)i4*4) = o1;
    int r = i4 / 28, c0 = (i4 % 28) * 4;
    #pragma unroll
    for (int j = 0; j < 4; ++j){
      ys[0][r][c0+j] = p0[j];
      ys[1][r][c0+j] = p1[j];
    }
  }
  #pragma unroll
  for (int off = 32; off; off >>= 1){
    s0 += __shfl_xor(s0, off, 64); q0 += __shfl_xor(q0, off, 64);
    s1 += __shfl_xor(s1, off, 64); q1 += __shfl_xor(q1, off, 64);
  }
  if (lane == 0){ redA[w][0] = s0; redA[w][1] = q0; redA[w][2] = s1; redA[w][3] = q1; }
  __syncthreads();
  if (tid == 0){
    float a0=0,a1=0,a2=0,a3=0;
    for (int i = 0; i < 8; ++i){ a0+=redA[i][0]; a1+=redA[i][1]; a2+=redA[i][2]; a3+=redA[i][3]; }
    float4 ps = {a0,a1,a2,a3};
    planeStats[bc] = ps;
  }
  __syncthreads();

  const int kk[3] = {3,5,7};
  const int gg[3] = {37,22,16};
  for (int pl = 0; pl < 2; ++pl){
    const int cc = pl*64 + c;
    for (int ki = 0; ki < 3; ++ki){
      const int k = kk[ki], g = gg[ki];
      float sumAll = 0.f, mx = -3.0e38f;
      for (int win = tid; win < g*g; win += 512){
        int wy = win / g, wx = win % g;
        float s = 0.f;
        for (int dy = 0; dy < k; ++dy)
          for (int dx = 0; dx < k; ++dx)
            s += bf2f(ys[pl][wy*k+dy][wx*k+dx]);
        sumAll += s; mx = fmaxf(mx, s);
      }
      #pragma unroll
      for (int off = 32; off; off >>= 1){
        sumAll += __shfl_xor(sumAll, off, 64);
        mx = fmaxf(mx, __shfl_xor(mx, off, 64));
      }
      if (lane == 0){ redS[w] = sumAll; redM[w] = mx; }
      __syncthreads();
      if (tid == 0){
        float st = 0.f, mt = -3.0e38f;
        for (int i = 0; i < 8; ++i){ st += redS[i]; mt = fmaxf(mt, redM[i]); }
        int idx = (b*128 + cc)*3 + ki;
        avgstat[idx] = st / (float)(k*k*g*g);
        maxstat[idx] = mt / (float)(k*k);
      }
      __syncthreads();
    }
  }
}

// ---------------- K6: channel-attention MLP ----------------
__global__ void k6_mlp(const float* __restrict__ avgstat, const float* __restrict__ maxstat,
    const float* __restrict__ lin1, const float* __restrict__ lin2,
    const float* __restrict__ w1, const float* __restrict__ w2,
    float* __restrict__ ca)
{
  const int b = blockIdx.x, tid = threadIdx.x; // 128 threads
  __shared__ float sa[128], sm[128], hA[16], hM[16];
  int idx = (b*128 + tid)*3;
  sa[tid] = avgstat[idx]*lin1[0] + avgstat[idx+1]*lin1[1] + avgstat[idx+2]*lin1[2];
  sm[tid] = maxstat[idx]*lin2[0] + maxstat[idx+1]*lin2[1] + maxstat[idx+2]*lin2[2];
  __syncthreads();
  if (tid < 16){
    float ha = 0.f, hm = 0.f;
    for (int c2 = 0; c2 < 128; ++c2){
      ha += w1[tid*128 + c2]*sa[c2];
      hm += w1[tid*128 + c2]*sm[c2];
    }
    hA[tid] = fmaxf(ha, 0.f); hM[tid] = fmaxf(hm, 0.f);
  }
  __syncthreads();
  float o = 0.f;
  for (int r = 0; r < 16; ++r) o += w2[tid*16 + r]*(hA[r] + hM[r]);
  ca[b*128 + tid] = 1.f/(1.f + __expf(-o));
}

// ---------------- K8: final bn affine from per-plane stats + ca ----------------
__global__ void k8_affineF(const float4* __restrict__ planeStats, const float* __restrict__ ca,
    const float* __restrict__ rgb_cw, const float* __restrict__ rgb_bg, const float* __restrict__ rgb_bb,
    const float* __restrict__ fre_cw, const float* __restrict__ fre_bg, const float* __restrict__ fre_bb,
    float* __restrict__ ABF)
{
  int t = threadIdx.x;
  if (t >= 128) return;
  int z = t >> 6, c = t & 63;
  float S = 0.f, Q = 0.f;
  for (int b = 0; b < 32; ++b){
    float4 ps = planeStats[b*64 + c];
    float sc = ca[b*128 + t];
    float sp = z ? ps.z : ps.x;
    float qp = z ? ps.w : ps.y;
    S += sc*sp; Q += sc*sc*qp;
  }
  const float n = 401408.f;
  float m = S/n, v = Q/n - m*m;
  float cw = z ? fre_cw[c] : rgb_cw[c];
  float g  = z ? fre_bg[c] : rgb_bg[c];
  float bb = z ? fre_bb[c] : rgb_bb[c];
  float rs = rsqrtf(cw*cw*v + EPSV);
  ABF[z*128 + c]      = cw*rs*g;
  ABF[z*128 + 64 + c] = -cw*m*rs*g + bb;
}

// ---------------- K9: out = y*(1 + A*ca) + B (bf16 y in, fp32 out) ----------------
__global__ __launch_bounds__(256) void k9_out(
    const unsigned short* __restrict__ ybf, const unsigned short* __restrict__ ybl,
    const float* __restrict__ ca, const float* __restrict__ ABF,
    float* __restrict__ out)
{
  const int c = blockIdx.x, b = blockIdx.y, z = blockIdx.z;
  const size_t plane = ((size_t)b*64 + c)*PP;
  const unsigned short* y = z ? ybl : ybf;
  float* o = out + (z ? NE : 0) + plane;
  const float sc = ca[b*128 + z*64 + c];
  const float A = ABF[z*128 + c], Bv = ABF[z*128 + 64 + c];
  const float mul = 1.f + A*sc;
  for (int i8 = threadIdx.x; i8 < 1568; i8 += 256){
    short8v yv = *(const short8v*)(y + plane + (size_t)i8*8);
    float4 o0, o1;
    o0.x = bf2f((unsigned short)yv[0])*mul + Bv;
    o0.y = bf2f((unsigned short)yv[1])*mul + Bv;
    o0.z = bf2f((unsigned short)yv[2])*mul + Bv;
    o0.w = bf2f((unsigned short)yv[3])*mul + Bv;
    o1.x = bf2f((unsigned short)yv[4])*mul + Bv;
    o1.y = bf2f((unsigned short)yv[5])*mul + Bv;
    o1.z = bf2f((unsigned short)yv[6])*mul + Bv;
    o1.w = bf2f((unsigned short)yv[7])*mul + Bv;
    *(float4*)(&o[(size_t)i8*8])     = o0;
    *(float4*)(&o[(size_t)i8*8 + 4]) = o1;
  }
}

extern "C" void kernel_launch(void* const* d_in, const int* in_sizes, int n_in,
                              void* d_out, int out_size, void* d_ws, size_t ws_size,
                              hipStream_t stream)
{
  (void)in_sizes; (void)n_in; (void)out_size; (void)ws_size;
  const float* rgb      = (const float*)d_in[0];
  const float* fre      = (const float*)d_in[1];
  const float* wq_fad   = (const float*)d_in[2];
  const float* bq_fad   = (const float*)d_in[3];
  const float* wq_lfs   = (const float*)d_in[4];
  const float* bq_lfs   = (const float*)d_in[5];
  const float* wk_fad   = (const float*)d_in[6];
  const float* bk_fad   = (const float*)d_in[7];
  const float* wk_lfs   = (const float*)d_in[8];
  const float* bk_lfs   = (const float*)d_in[9];
  const float* fad_gamma= (const float*)d_in[10];
  const float* lfs_gamma= (const float*)d_in[11];
  const float* fad_cw   = (const float*)d_in[12];
  const float* fad_bg   = (const float*)d_in[14];
  const float* fad_bb   = (const float*)d_in[15];
  const float* lfs_cw   = (const float*)d_in[16];
  const float* lfs_bg   = (const float*)d_in[18];
  const float* lfs_bb   = (const float*)d_in[19];
  const float* lin1_w   = (const float*)d_in[20];
  const float* lin2_w   = (const float*)d_in[21];
  const float* mlp_w1   = (const float*)d_in[22];
  const float* mlp_w2   = (const float*)d_in[23];
  const float* rgb_cw   = (const float*)d_in[24];
  const float* rgb_bg   = (const float*)d_in[26];
  const float* rgb_bb   = (const float*)d_in[27];
  const float* fre_cw   = (const float*)d_in[28];
  const float* fre_bg   = (const float*)d_in[30];
  const float* fre_bb   = (const float*)d_in[31];

  char* ws = (char*)d_ws;
  unsigned short* qF = (unsigned short*)(ws);          // becomes attn after k2
  unsigned short* qL = (unsigned short*)(ws + 2*NE);
  unsigned short* kF = (unsigned short*)(ws + 4*NE);   // becomes y_fad (bf16) after k4
  unsigned short* kL = (unsigned short*)(ws + 6*NE);   // becomes y_lfs (bf16) after k4
  float* sbase = (float*)(ws + 8*NE);
  float* stats      = sbase;               // [0..255]   bn1 atomics (memset)
  float* AB1        = sbase + 256;
  float* avgstat    = sbase + 512;
  float* maxstat    = sbase + 12800;
  float* ca         = sbase + 25088;
  float* ABF        = sbase + 29184;
  float4* planeStats= (float4*)(sbase + 29440);
  // bf16 copies of rgb/fre live in the FIRST HALF of d_out; consumed by k2/k4,
  // then k9 overwrites all of d_out. Rewritten every call.
  unsigned short* rgbb = (unsigned short*)d_out;
  unsigned short* freb = (unsigned short*)d_out + NE;

  hipMemsetAsync(stats, 0, 256*sizeof(float), stream);

  k1_conv<<<dim3(49,32,2), dim3(256), 0, stream>>>(rgb, fre,
      wq_fad, bq_fad, wk_fad, bk_fad, wq_lfs, bq_lfs, wk_lfs, bk_lfs,
      qF, kF, qL, kL, rgbb, freb);
  k2_attn<<<dim3(2048), dim3(448), 0, stream>>>(qF, qL, kF, kL,
      rgbb, freb, fad_gamma, lfs_gamma, stats);
  k3_affine1<<<dim3(1), dim3(64), 0, stream>>>(stats,
      fad_cw, fad_bg, fad_bb, lfs_cw, lfs_bg, lfs_bb, AB1);
  k4_fuse<<<dim3(2048), dim3(512), 0, stream>>>((const unsigned short*)qF,
      rgbb, freb, AB1, fad_gamma, lfs_gamma, kF, kL, avgstat, maxstat, planeStats);
  k6_mlp<<<dim3(32), dim3(128), 0, stream>>>(avgstat, maxstat,
      lin1_w, lin2_w, mlp_w1, mlp_w2, ca);
  k8_affineF<<<dim3(1), dim3(128), 0, stream>>>(planeStats, ca,
      rgb_cw, rgb_bg, rgb_bb, fre_cw, fre_bg, fre_bb, ABF);
  k9_out<<<dim3(64,32,2), dim3(256), 0, stream>>>(kF, kL, ca, ABF,
      (float*)d_out);
}

// Round 6
// 424.976 us; speedup vs baseline: 2.3119x; 1.0502x over previous
//
#include <hip/hip_runtime.h>
#include <hip/hip_bf16.h>
#include <stdint.h>

#define NE 25690112ull   // 32*64*112*112
#define PP 12544         // 112*112
#define SS 112
#define EPSV 1e-5f

typedef __attribute__((ext_vector_type(8))) short short8v;
typedef __attribute__((ext_vector_type(4))) float float4v;

__device__ __forceinline__ unsigned short f2bf(float x){
  union { float f; uint32_t u; } v; v.f = x;
  uint32_t r = (v.u + 0x7fffu + ((v.u >> 16) & 1u)) >> 16;
  return (unsigned short)r;
}
__device__ __forceinline__ float bf2f(unsigned short u){ return __uint_as_float(((uint32_t)u) << 16); }

// ---------------- K1: conv1x1 via MFMA ----------------
// Phase A: row-contiguous loads (1KB/instr), single conversion, 512B-coalesced
// bf16 copy stores, natural [c][p] LDS staging (pitch 260 u16).
// Phase B: fragment gather via scalar u16 LDS reads (transpose happens here).
// Phase C/D: MFMA with weights in regs, D staged to LDS, 512B-coalesced stores.
__global__ __launch_bounds__(256) void k1_conv(
    const float* __restrict__ rgb, const float* __restrict__ fre,
    const float* __restrict__ wq_fad, const float* __restrict__ bq_fad,
    const float* __restrict__ wk_fad, const float* __restrict__ bk_fad,
    const float* __restrict__ wq_lfs, const float* __restrict__ bq_lfs,
    const float* __restrict__ wk_lfs, const float* __restrict__ bk_lfs,
    unsigned short* __restrict__ qF, unsigned short* __restrict__ kF,
    unsigned short* __restrict__ qL, unsigned short* __restrict__ kL,
    unsigned short* __restrict__ rgbb, unsigned short* __restrict__ freb)
{
  const int bx = blockIdx.x, b = blockIdx.y, z = blockIdx.z;
  const float* X  = z ? fre : rgb;
  const float* Wq = z ? wq_lfs : wq_fad;
  const float* Bq = z ? bq_lfs : bq_fad;
  const float* Wk = z ? wk_lfs : wk_fad;
  const float* Bk = z ? bk_lfs : bk_fad;
  unsigned short* Oq = z ? qL : qF;
  unsigned short* Ok = z ? kL : kF;
  unsigned short* Xb = z ? freb : rgbb;

  __shared__ __align__(16) unsigned short xs[64 * 260];  // 33.3 KB; also reused for D staging (32 KB)

  const int tid = threadIdx.x, lane = tid & 63, w = tid >> 6;
  const int lc = lane & 15, l4 = lane >> 4;

  // ---- Phase A: one row per instruction, 1KB contiguous; copy store 512B ----
  const int p0 = bx*256;
  const size_t xbase = (size_t)b * 64 * PP;
  #pragma unroll
  for (int i = 0; i < 16; ++i){
    const int c = w*16 + i;
    const size_t gof = xbase + (size_t)c*PP + p0 + lane*4;
    float4 xv = *(const float4*)(X + gof);
    ushort4 s;
    s.x = f2bf(xv.x); s.y = f2bf(xv.y); s.z = f2bf(xv.z); s.w = f2bf(xv.w);
    *(ushort4*)(Xb + gof) = s;                    // 64 lanes x 8B = 512B contiguous
    *(ushort4*)(&xs[c*260 + lane*4]) = s;         // conflict-free LDS write
  }
  __syncthreads();

  // ---- Phase B: gather A-frags (transpose): A[p=pt+lc][c=ks*32+l4*8+j] ----
  short8v afr[4][2];
  #pragma unroll
  for (int t = 0; t < 4; ++t){
    const int p = (t*4 + w)*16 + lc;
    #pragma unroll
    for (int ks = 0; ks < 2; ++ks){
      short8v a;
      #pragma unroll
      for (int j = 0; j < 8; ++j)
        a[j] = (short)xs[(ks*32 + l4*8 + j)*260 + p];
      afr[t][ks] = a;
    }
  }
  __syncthreads();

  // ---- Phase C/D: per array {Q,K}: compute -> D to LDS [o][256p] -> coalesced store
  #pragma unroll
  for (int arr = 0; arr < 2; ++arr){
    const float* W = arr ? Wk : Wq;
    const float* Bi = arr ? Bk : Bq;
    unsigned short* O = arr ? Ok : Oq;
    short8v wf[4][2];
    float bias[4];
    #pragma unroll
    for (int ot = 0; ot < 4; ++ot){
      bias[ot] = Bi[ot*16 + lc];
      #pragma unroll
      for (int ks = 0; ks < 2; ++ks){
        const int base = (ot*16 + lc)*64 + ks*32 + l4*8;
        const float4 q0 = *(const float4*)(W + base);
        const float4 q1 = *(const float4*)(W + base + 4);
        short8v v;
        v[0]=(short)f2bf(q0.x); v[1]=(short)f2bf(q0.y); v[2]=(short)f2bf(q0.z); v[3]=(short)f2bf(q0.w);
        v[4]=(short)f2bf(q1.x); v[5]=(short)f2bf(q1.y); v[6]=(short)f2bf(q1.z); v[7]=(short)f2bf(q1.w);
        wf[ot][ks] = v;
      }
    }
    #pragma unroll
    for (int t = 0; t < 4; ++t){
      const int pt = (t*4 + w)*16;
      #pragma unroll
      for (int ot = 0; ot < 4; ++ot){
        float4v acc = (float4v){bias[ot], bias[ot], bias[ot], bias[ot]};
        acc = __builtin_amdgcn_mfma_f32_16x16x32_bf16(afr[t][0], wf[ot][0], acc, 0, 0, 0);
        acc = __builtin_amdgcn_mfma_f32_16x16x32_bf16(afr[t][1], wf[ot][1], acc, 0, 0, 0);
        ushort4 u;
        u.x = f2bf(acc[0]); u.y = f2bf(acc[1]); u.z = f2bf(acc[2]); u.w = f2bf(acc[3]);
        const int o = ot*16 + lc;
        uint32_t byteS = (uint32_t)(o*512 + (pt + l4*4)*2) ^ (uint32_t)((o & 7) << 4);
        *(ushort4*)((char*)xs + byteS) = u;
      }
    }
    __syncthreads();
    for (int i = tid; i < 2048; i += 256){
      const int o = i >> 5, s = i & 31;
      uint32_t byteS = (uint32_t)(o*512 + s*16) ^ (uint32_t)((o & 7) << 4);
      short8v v = *(const short8v*)((const char*)xs + byteS);
      *(short8v*)(O + ((size_t)b*64 + o)*PP + p0 + s*8) = v;
    }
    __syncthreads();
  }
}

// ---------------- K2: MFMA attention, LDS-staged coalesced epilogue ----------------
__global__ __launch_bounds__(448) void k2_attn(
    unsigned short* __restrict__ qF, const unsigned short* __restrict__ qL,
    const unsigned short* __restrict__ kF, const unsigned short* __restrict__ kL,
    const unsigned short* __restrict__ rgbb, const unsigned short* __restrict__ freb,
    const float* __restrict__ fad_gamma, const float* __restrict__ lfs_gamma,
    float* __restrict__ stats)
{
  const int bc = blockIdx.x, c = bc & 63;
  const size_t plane = (size_t)bc * PP;
  __shared__ __align__(16) unsigned short ksF[112][128];
  __shared__ __align__(16) unsigned short ksL[112][128];
  const int tid = threadIdx.x, lane = tid & 63, w = tid >> 6;
  const int l4 = lane >> 4, lc = lane & 15;

  const uint32_t* kFu = (const uint32_t*)kF + plane/2;
  const uint32_t* kLu = (const uint32_t*)kL + plane/2;
  for (int i = tid; i < 7168; i += 448){
    int row = i >> 6, wd = i & 63;
    uint32_t vF = (wd < 56) ? kFu[row*56 + wd] : 0u;
    uint32_t vL = (wd < 56) ? kLu[row*56 + wd] : 0u;
    uint32_t byteS = (uint32_t)((row << 8) | (wd << 2)) ^ (uint32_t)((row & 7) << 4);
    *(uint32_t*)((char*)&ksF[0][0] + byteS) = vF;
    *(uint32_t*)((char*)&ksL[0][0] + byteS) = vL;
  }
  __syncthreads();

  float4v acc[7];
  #pragma unroll
  for (int ct = 0; ct < 7; ++ct) acc[ct] = (float4v)0.f;

  const unsigned short* qFp = qF + plane;
  const unsigned short* qLp = qL + plane;
  const int qrow = w*16 + lc;
  #pragma unroll
  for (int ks = 0; ks < 4; ++ks){
    short8v aF = (short8v)(short)0, aL = (short8v)(short)0;
    const int joff = ks*32 + l4*8;
    if ((ks < 3) || (l4 < 2)){
      aF = *(const short8v*)(qFp + qrow*SS + joff);
      aL = *(const short8v*)(qLp + qrow*SS + joff);
    }
    #pragma unroll
    for (int ct = 0; ct < 7; ++ct){
      uint32_t byteS = (uint32_t)((ct*16 + lc)*256 + ks*64 + l4*16) ^ (uint32_t)((lc & 7) << 4);
      short8v bF = *(const short8v*)((const char*)&ksF[0][0] + byteS);
      short8v bL = *(const short8v*)((const char*)&ksL[0][0] + byteS);
      acc[ct] = __builtin_amdgcn_mfma_f32_16x16x32_bf16(aF, bF, acc[ct], 0, 0, 0);
      acc[ct] = __builtin_amdgcn_mfma_f32_16x16x32_bf16(aL, bL, acc[ct], 0, 0, 0);
    }
  }

  const float sF = 2.f/(1.f + __expf(-fad_gamma[0])) - 1.f;
  const float sL = 2.f/(1.f + __expf(-lfs_gamma[0])) - 1.f;
  unsigned short* attnP = qF + plane;
  unsigned short* alin = &ksF[0][0];   // dead after MFMA: reuse as [112*112] attn staging

  __syncthreads();   // all waves done reading ksF/ksL
  #pragma unroll
  for (int r = 0; r < 4; ++r){
    const int i = w*16 + l4*4 + r;
    float v[7];
    #pragma unroll
    for (int ct = 0; ct < 7; ++ct) v[ct] = acc[ct][r];
    float m = fmaxf(fmaxf(fmaxf(v[0],v[1]),fmaxf(v[2],v[3])), fmaxf(fmaxf(v[4],v[5]),v[6]));
    #pragma unroll
    for (int off = 8; off; off >>= 1) m = fmaxf(m, __shfl_xor(m, off, 64));
    float e[7]; float s = 0.f;
    #pragma unroll
    for (int ct = 0; ct < 7; ++ct){ e[ct] = __expf(v[ct] - m); s += e[ct]; }
    #pragma unroll
    for (int off = 8; off; off >>= 1) s += __shfl_xor(s, off, 64);
    const float inv = 1.f / s;
    #pragma unroll
    for (int ct = 0; ct < 7; ++ct)
      alin[i*SS + ct*16 + lc] = f2bf(e[ct] * inv);
  }
  __syncthreads();

  // coalesced pass: attn write (512B/instr) + stat reads (512B/instr)
  float ls1 = 0.f, lq1 = 0.f, ls2 = 0.f, lq2 = 0.f;
  for (int i4 = tid; i4 < 3136; i4 += 448){
    ushort4 av = *(const ushort4*)(alin + i4*4);
    *(ushort4*)(attnP + (size_t)i4*4) = av;
    ushort4 fr = *(const ushort4*)(freb + plane + (size_t)i4*4);
    ushort4 rg = *(const ushort4*)(rgbb + plane + (size_t)i4*4);
    const unsigned short* ap = &av.x;
    const unsigned short* fp = &fr.x;
    const unsigned short* rp = &rg.x;
    #pragma unroll
    for (int j = 0; j < 4; ++j){
      float a = bf2f(ap[j]);
      float v1 = bf2f(fp[j]) * a * sL;
      float v2 = bf2f(rp[j]) * a * sF;
      ls1 += v1; lq1 += v1*v1; ls2 += v2; lq2 += v2*v2;
    }
  }
  #pragma unroll
  for (int off = 32; off; off >>= 1){
    ls1 += __shfl_xor(ls1, off, 64);
    lq1 += __shfl_xor(lq1, off, 64);
    ls2 += __shfl_xor(ls2, off, 64);
    lq2 += __shfl_xor(lq2, off, 64);
  }
  if (lane == 0){
    atomicAdd(&stats[c],       ls1);
    atomicAdd(&stats[64 + c],  lq1);
    atomicAdd(&stats[128 + c], ls2);
    atomicAdd(&stats[192 + c], lq2);
  }
}

// ---------------- K3: bn1 stats -> affine ----------------
__global__ void k3_affine1(const float* __restrict__ stats,
    const float* __restrict__ fad_cw, const float* __restrict__ fad_bg, const float* __restrict__ fad_bb,
    const float* __restrict__ lfs_cw, const float* __restrict__ lfs_bg, const float* __restrict__ lfs_bb,
    float* __restrict__ AB)
{
  int c = threadIdx.x;
  if (c >= 64) return;
  const float n = 401408.f;
  {
    float m1 = stats[c]/n, v1 = stats[64+c]/n - (stats[c]/n)*(stats[c]/n);
    float cw = fad_cw[c], g = fad_bg[c];
    float rs = rsqrtf(cw*cw*v1 + EPSV);
    AB[c]      = cw*rs*g;
    AB[64 + c] = -cw*m1*rs*g + fad_bb[c];
  }
  {
    float m2 = stats[128+c]/n, v2 = stats[192+c]/n - (stats[128+c]/n)*(stats[128+c]/n);
    float cw = lfs_cw[c], g = lfs_bg[c];
    float rs = rsqrtf(cw*cw*v2 + EPSV);
    AB[128 + c] = cw*rs*g;
    AB[192 + c] = -cw*m2*rs*g + lfs_bb[c];
  }
}

// ---------------- K4: fused y (bf16 out) + pooling + per-plane stats ----------------
__global__ __launch_bounds__(512) void k4_fuse(
    const unsigned short* __restrict__ attn,
    const unsigned short* __restrict__ rgbb, const unsigned short* __restrict__ freb,
    const float* __restrict__ AB1,
    const float* __restrict__ fad_gamma, const float* __restrict__ lfs_gamma,
    unsigned short* __restrict__ ybf, unsigned short* __restrict__ ybl,
    float* __restrict__ avgstat, float* __restrict__ maxstat,
    float4* __restrict__ planeStats)
{
  const int bc = blockIdx.x, b = bc >> 6, c = bc & 63;
  const size_t plane = (size_t)bc * PP;
  __shared__ unsigned short ys[2][112][113];
  __shared__ float redA[8][4];
  __shared__ float redS[8], redM[8];
  const int tid = threadIdx.x, lane = tid & 63, w = tid >> 6;
  const float sF = 2.f/(1.f + __expf(-fad_gamma[0])) - 1.f;
  const float sL = 2.f/(1.f + __expf(-lfs_gamma[0])) - 1.f;
  const float A1 = AB1[c], B1 = AB1[64+c], A2 = AB1[128+c], B2 = AB1[192+c];
  float s0 = 0.f, q0 = 0.f, s1 = 0.f, q1 = 0.f;

  for (int i4 = tid; i4 < 3136; i4 += 512){
    ushort4 av = *(const ushort4*)(attn + plane + (size_t)i4*4);
    ushort4 rg = *(const ushort4*)(rgbb + plane + (size_t)i4*4);
    ushort4 fr = *(const ushort4*)(freb + plane + (size_t)i4*4);
    float aa[4] = {bf2f(av.x), bf2f(av.y), bf2f(av.z), bf2f(av.w)};
    float rr[4] = {bf2f(rg.x), bf2f(rg.y), bf2f(rg.z), bf2f(rg.w)};
    float ff[4] = {bf2f(fr.x), bf2f(fr.y), bf2f(fr.z), bf2f(fr.w)};
    float y0[4], y1[4];
    ushort4 o0, o1;
    unsigned short* p0 = &o0.x; unsigned short* p1 = &o1.x;
    #pragma unroll
    for (int j = 0; j < 4; ++j){
      float t1 = ff[j]*aa[j]*sL;
      float t2 = rr[j]*aa[j]*sF;
      y0[j] = rr[j] + A1*t1 + B1;
      y1[j] = ff[j] + A2*t2 + B2;
      s0 += y0[j]; q0 += y0[j]*y0[j];
      s1 += y1[j]; q1 += y1[j]*y1[j];
      p0[j] = f2bf(y0[j]);
      p1[j] = f2bf(y1[j]);
    }
    *(ushort4*)(ybf + plane + (size_t)i4*4) = o0;
    *(ushort4*)(ybl + plane + (size_t)i4*4) = o1;
    int r = i4 / 28, c0 = (i4 % 28) * 4;
    #pragma unroll
    for (int j = 0; j < 4; ++j){
      ys[0][r][c0+j] = p0[j];
      ys[1][r][c0+j] = p1[j];
    }
  }
  #pragma unroll
  for (int off = 32; off; off >>= 1){
    s0 += __shfl_xor(s0, off, 64); q0 += __shfl_xor(q0, off, 64);
    s1 += __shfl_xor(s1, off, 64); q1 += __shfl_xor(q1, off, 64);
  }
  if (lane == 0){ redA[w][0] = s0; redA[w][1] = q0; redA[w][2] = s1; redA[w][3] = q1; }
  __syncthreads();
  if (tid == 0){
    float a0=0,a1=0,a2=0,a3=0;
    for (int i = 0; i < 8; ++i){ a0+=redA[i][0]; a1+=redA[i][1]; a2+=redA[i][2]; a3+=redA[i][3]; }
    float4 ps = {a0,a1,a2,a3};
    planeStats[bc] = ps;
  }
  __syncthreads();

  const int kk[3] = {3,5,7};
  const int gg[3] = {37,22,16};
  for (int pl = 0; pl < 2; ++pl){
    const int cc = pl*64 + c;
    for (int ki = 0; ki < 3; ++ki){
      const int k = kk[ki], g = gg[ki];
      float sumAll = 0.f, mx = -3.0e38f;
      for (int win = tid; win < g*g; win += 512){
        int wy = win / g, wx = win % g;
        float s = 0.f;
        for (int dy = 0; dy < k; ++dy)
          for (int dx = 0; dx < k; ++dx)
            s += bf2f(ys[pl][wy*k+dy][wx*k+dx]);
        sumAll += s; mx = fmaxf(mx, s);
      }
      #pragma unroll
      for (int off = 32; off; off >>= 1){
        sumAll += __shfl_xor(sumAll, off, 64);
        mx = fmaxf(mx, __shfl_xor(mx, off, 64));
      }
      if (lane == 0){ redS[w] = sumAll; redM[w] = mx; }
      __syncthreads();
      if (tid == 0){
        float st = 0.f, mt = -3.0e38f;
        for (int i = 0; i < 8; ++i){ st += redS[i]; mt = fmaxf(mt, redM[i]); }
        int idx = (b*128 + cc)*3 + ki;
        avgstat[idx] = st / (float)(k*k*g*g);
        maxstat[idx] = mt / (float)(k*k);
      }
      __syncthreads();
    }
  }
}

// ---------------- K6: channel-attention MLP ----------------
__global__ void k6_mlp(const float* __restrict__ avgstat, const float* __restrict__ maxstat,
    const float* __restrict__ lin1, const float* __restrict__ lin2,
    const float* __restrict__ w1, const float* __restrict__ w2,
    float* __restrict__ ca)
{
  const int b = blockIdx.x, tid = threadIdx.x; // 128 threads
  __shared__ float sa[128], sm[128], hA[16], hM[16];
  int idx = (b*128 + tid)*3;
  sa[tid] = avgstat[idx]*lin1[0] + avgstat[idx+1]*lin1[1] + avgstat[idx+2]*lin1[2];
  sm[tid] = maxstat[idx]*lin2[0] + maxstat[idx+1]*lin2[1] + maxstat[idx+2]*lin2[2];
  __syncthreads();
  if (tid < 16){
    float ha = 0.f, hm = 0.f;
    for (int c2 = 0; c2 < 128; ++c2){
      ha += w1[tid*128 + c2]*sa[c2];
      hm += w1[tid*128 + c2]*sm[c2];
    }
    hA[tid] = fmaxf(ha, 0.f); hM[tid] = fmaxf(hm, 0.f);
  }
  __syncthreads();
  float o = 0.f;
  for (int r = 0; r < 16; ++r) o += w2[tid*16 + r]*(hA[r] + hM[r]);
  ca[b*128 + tid] = 1.f/(1.f + __expf(-o));
}

// ---------------- K8: final bn affine from per-plane stats + ca ----------------
__global__ void k8_affineF(const float4* __restrict__ planeStats, const float* __restrict__ ca,
    const float* __restrict__ rgb_cw, const float* __restrict__ rgb_bg, const float* __restrict__ rgb_bb,
    const float* __restrict__ fre_cw, const float* __restrict__ fre_bg, const float* __restrict__ fre_bb,
    float* __restrict__ ABF)
{
  int t = threadIdx.x;
  if (t >= 128) return;
  int z = t >> 6, c = t & 63;
  float S = 0.f, Q = 0.f;
  for (int b = 0; b < 32; ++b){
    float4 ps = planeStats[b*64 + c];
    float sc = ca[b*128 + t];
    float sp = z ? ps.z : ps.x;
    float qp = z ? ps.w : ps.y;
    S += sc*sp; Q += sc*sc*qp;
  }
  const float n = 401408.f;
  float m = S/n, v = Q/n - m*m;
  float cw = z ? fre_cw[c] : rgb_cw[c];
  float g  = z ? fre_bg[c] : rgb_bg[c];
  float bb = z ? fre_bb[c] : rgb_bb[c];
  float rs = rsqrtf(cw*cw*v + EPSV);
  ABF[z*128 + c]      = cw*rs*g;
  ABF[z*128 + 64 + c] = -cw*m*rs*g + bb;
}

// ---------------- K9: out = y*(1 + A*ca) + B (bf16 y in, fp32 out) ----------------
__global__ __launch_bounds__(256) void k9_out(
    const unsigned short* __restrict__ ybf, const unsigned short* __restrict__ ybl,
    const float* __restrict__ ca, const float* __restrict__ ABF,
    float* __restrict__ out)
{
  const int c = blockIdx.x, b = blockIdx.y, z = blockIdx.z;
  const size_t plane = ((size_t)b*64 + c)*PP;
  const unsigned short* y = z ? ybl : ybf;
  float* o = out + (z ? NE : 0) + plane;
  const float sc = ca[b*128 + z*64 + c];
  const float A = ABF[z*128 + c], Bv = ABF[z*128 + 64 + c];
  const float mul = 1.f + A*sc;
  for (int i8 = threadIdx.x; i8 < 1568; i8 += 256){
    short8v yv = *(const short8v*)(y + plane + (size_t)i8*8);
    float4 o0, o1;
    o0.x = bf2f((unsigned short)yv[0])*mul + Bv;
    o0.y = bf2f((unsigned short)yv[1])*mul + Bv;
    o0.z = bf2f((unsigned short)yv[2])*mul + Bv;
    o0.w = bf2f((unsigned short)yv[3])*mul + Bv;
    o1.x = bf2f((unsigned short)yv[4])*mul + Bv;
    o1.y = bf2f((unsigned short)yv[5])*mul + Bv;
    o1.z = bf2f((unsigned short)yv[6])*mul + Bv;
    o1.w = bf2f((unsigned short)yv[7])*mul + Bv;
    *(float4*)(&o[(size_t)i8*8])     = o0;
    *(float4*)(&o[(size_t)i8*8 + 4]) = o1;
  }
}

extern "C" void kernel_launch(void* const* d_in, const int* in_sizes, int n_in,
                              void* d_out, int out_size, void* d_ws, size_t ws_size,
                              hipStream_t stream)
{
  (void)in_sizes; (void)n_in; (void)out_size; (void)ws_size;
  const float* rgb      = (const float*)d_in[0];
  const float* fre      = (const float*)d_in[1];
  const float* wq_fad   = (const float*)d_in[2];
  const float* bq_fad   = (const float*)d_in[3];
  const float* wq_lfs   = (const float*)d_in[4];
  const float* bq_lfs   = (const float*)d_in[5];
  const float* wk_fad   = (const float*)d_in[6];
  const float* bk_fad   = (const float*)d_in[7];
  const float* wk_lfs   = (const float*)d_in[8];
  const float* bk_lfs   = (const float*)d_in[9];
  const float* fad_gamma= (const float*)d_in[10];
  const float* lfs_gamma= (const float*)d_in[11];
  const float* fad_cw   = (const float*)d_in[12];
  const float* fad_bg   = (const float*)d_in[14];
  const float* fad_bb   = (const float*)d_in[15];
  const float* lfs_cw   = (const float*)d_in[16];
  const float* lfs_bg   = (const float*)d_in[18];
  const float* lfs_bb   = (const float*)d_in[19];
  const float* lin1_w   = (const float*)d_in[20];
  const float* lin2_w   = (const float*)d_in[21];
  const float* mlp_w1   = (const float*)d_in[22];
  const float* mlp_w2   = (const float*)d_in[23];
  const float* rgb_cw   = (const float*)d_in[24];
  const float* rgb_bg   = (const float*)d_in[26];
  const float* rgb_bb   = (const float*)d_in[27];
  const float* fre_cw   = (const float*)d_in[28];
  const float* fre_bg   = (const float*)d_in[30];
  const float* fre_bb   = (const float*)d_in[31];

  char* ws = (char*)d_ws;
  unsigned short* qF = (unsigned short*)(ws);          // becomes attn after k2
  unsigned short* qL = (unsigned short*)(ws + 2*NE);
  unsigned short* kF = (unsigned short*)(ws + 4*NE);   // becomes y_fad (bf16) after k4
  unsigned short* kL = (unsigned short*)(ws + 6*NE);   // becomes y_lfs (bf16) after k4
  float* sbase = (float*)(ws + 8*NE);
  float* stats      = sbase;               // [0..255]   bn1 atomics (memset)
  float* AB1        = sbase + 256;
  float* avgstat    = sbase + 512;
  float* maxstat    = sbase + 12800;
  float* ca         = sbase + 25088;
  float* ABF        = sbase + 29184;
  float4* planeStats= (float4*)(sbase + 29440);
  // bf16 copies of rgb/fre live in the FIRST HALF of d_out; consumed by k2/k4,
  // then k9 overwrites all of d_out. Rewritten every call.
  unsigned short* rgbb = (unsigned short*)d_out;
  unsigned short* freb = (unsigned short*)d_out + NE;

  hipMemsetAsync(stats, 0, 256*sizeof(float), stream);

  k1_conv<<<dim3(49,32,2), dim3(256), 0, stream>>>(rgb, fre,
      wq_fad, bq_fad, wk_fad, bk_fad, wq_lfs, bq_lfs, wk_lfs, bk_lfs,
      qF, kF, qL, kL, rgbb, freb);
  k2_attn<<<dim3(2048), dim3(448), 0, stream>>>(qF, qL, kF, kL,
      rgbb, freb, fad_gamma, lfs_gamma, stats);
  k3_affine1<<<dim3(1), dim3(64), 0, stream>>>(stats,
      fad_cw, fad_bg, fad_bb, lfs_cw, lfs_bg, lfs_bb, AB1);
  k4_fuse<<<dim3(2048), dim3(512), 0, stream>>>((const unsigned short*)qF,
      rgbb, freb, AB1, fad_gamma, lfs_gamma, kF, kL, avgstat, maxstat, planeStats);
  k6_mlp<<<dim3(32), dim3(128), 0, stream>>>(avgstat, maxstat,
      lin1_w, lin2_w, mlp_w1, mlp_w2, ca);
  k8_affineF<<<dim3(1), dim3(128), 0, stream>>>(planeStats, ca,
      rgb_cw, rgb_bg, rgb_bb, fre_cw, fre_bg, fre_bb, ABF);
  k9_out<<<dim3(64,32,2), dim3(256), 0, stream>>>(kF, kL, ca, ABF,
      (float*)d_out);
}

// Round 7
// 399.389 us; speedup vs baseline: 2.4601x; 1.0641x over previous
//
#include <hip/hip_runtime.h>
#include <hip/hip_bf16.h>
#include <stdint.h>

#define NE 25690112ull   // 32*64*112*112
#define PP 12544         // 112*112
#define SS 112
#define EPSV 1e-5f

typedef __attribute__((ext_vector_type(8))) short short8v;
typedef __attribute__((ext_vector_type(4))) float float4v;

__device__ __forceinline__ unsigned short f2bf(float x){
  union { float f; uint32_t u; } v; v.f = x;
  uint32_t r = (v.u + 0x7fffu + ((v.u >> 16) & 1u)) >> 16;
  return (unsigned short)r;
}
__device__ __forceinline__ float bf2f(unsigned short u){ return __uint_as_float(((uint32_t)u) << 16); }

// ---------------- K1: conv1x1 via MFMA (unchanged from round 5) ----------------
__global__ __launch_bounds__(256) void k1_conv(
    const float* __restrict__ rgb, const float* __restrict__ fre,
    const float* __restrict__ wq_fad, const float* __restrict__ bq_fad,
    const float* __restrict__ wk_fad, const float* __restrict__ bk_fad,
    const float* __restrict__ wq_lfs, const float* __restrict__ bq_lfs,
    const float* __restrict__ wk_lfs, const float* __restrict__ bk_lfs,
    unsigned short* __restrict__ qF, unsigned short* __restrict__ kF,
    unsigned short* __restrict__ qL, unsigned short* __restrict__ kL,
    unsigned short* __restrict__ rgbb, unsigned short* __restrict__ freb)
{
  const int bx = blockIdx.x, b = blockIdx.y, z = blockIdx.z;
  const float* X  = z ? fre : rgb;
  const float* Wq = z ? wq_lfs : wq_fad;
  const float* Bq = z ? bq_lfs : bq_fad;
  const float* Wk = z ? wk_lfs : wk_fad;
  const float* Bk = z ? bk_lfs : bk_fad;
  unsigned short* Oq = z ? qL : qF;
  unsigned short* Ok = z ? kL : kF;
  unsigned short* Xb = z ? freb : rgbb;

  __shared__ __align__(16) unsigned short xs[64 * 260];

  const int tid = threadIdx.x, lane = tid & 63, w = tid >> 6;
  const int lc = lane & 15, l4 = lane >> 4;

  const int p0 = bx*256;
  const size_t xbase = (size_t)b * 64 * PP;
  #pragma unroll
  for (int i = 0; i < 16; ++i){
    const int c = w*16 + i;
    const size_t gof = xbase + (size_t)c*PP + p0 + lane*4;
    float4 xv = *(const float4*)(X + gof);
    ushort4 s;
    s.x = f2bf(xv.x); s.y = f2bf(xv.y); s.z = f2bf(xv.z); s.w = f2bf(xv.w);
    *(ushort4*)(Xb + gof) = s;
    *(ushort4*)(&xs[c*260 + lane*4]) = s;
  }
  __syncthreads();

  short8v afr[4][2];
  #pragma unroll
  for (int t = 0; t < 4; ++t){
    const int p = (t*4 + w)*16 + lc;
    #pragma unroll
    for (int ks = 0; ks < 2; ++ks){
      short8v a;
      #pragma unroll
      for (int j = 0; j < 8; ++j)
        a[j] = (short)xs[(ks*32 + l4*8 + j)*260 + p];
      afr[t][ks] = a;
    }
  }
  __syncthreads();

  #pragma unroll
  for (int arr = 0; arr < 2; ++arr){
    const float* W = arr ? Wk : Wq;
    const float* Bi = arr ? Bk : Bq;
    unsigned short* O = arr ? Ok : Oq;
    short8v wf[4][2];
    float bias[4];
    #pragma unroll
    for (int ot = 0; ot < 4; ++ot){
      bias[ot] = Bi[ot*16 + lc];
      #pragma unroll
      for (int ks = 0; ks < 2; ++ks){
        const int base = (ot*16 + lc)*64 + ks*32 + l4*8;
        const float4 q0 = *(const float4*)(W + base);
        const float4 q1 = *(const float4*)(W + base + 4);
        short8v v;
        v[0]=(short)f2bf(q0.x); v[1]=(short)f2bf(q0.y); v[2]=(short)f2bf(q0.z); v[3]=(short)f2bf(q0.w);
        v[4]=(short)f2bf(q1.x); v[5]=(short)f2bf(q1.y); v[6]=(short)f2bf(q1.z); v[7]=(short)f2bf(q1.w);
        wf[ot][ks] = v;
      }
    }
    #pragma unroll
    for (int t = 0; t < 4; ++t){
      const int pt = (t*4 + w)*16;
      #pragma unroll
      for (int ot = 0; ot < 4; ++ot){
        float4v acc = (float4v){bias[ot], bias[ot], bias[ot], bias[ot]};
        acc = __builtin_amdgcn_mfma_f32_16x16x32_bf16(afr[t][0], wf[ot][0], acc, 0, 0, 0);
        acc = __builtin_amdgcn_mfma_f32_16x16x32_bf16(afr[t][1], wf[ot][1], acc, 0, 0, 0);
        ushort4 u;
        u.x = f2bf(acc[0]); u.y = f2bf(acc[1]); u.z = f2bf(acc[2]); u.w = f2bf(acc[3]);
        const int o = ot*16 + lc;
        uint32_t byteS = (uint32_t)(o*512 + (pt + l4*4)*2) ^ (uint32_t)((o & 7) << 4);
        *(ushort4*)((char*)xs + byteS) = u;
      }
    }
    __syncthreads();
    for (int i = tid; i < 2048; i += 256){
      const int o = i >> 5, s = i & 31;
      uint32_t byteS = (uint32_t)(o*512 + s*16) ^ (uint32_t)((o & 7) << 4);
      short8v v = *(const short8v*)((const char*)xs + byteS);
      *(short8v*)(O + ((size_t)b*64 + o)*PP + p0 + s*8) = v;
    }
    __syncthreads();
  }
}

// ---------------- K2: MFMA attention v2 ----------------
// Linear-pitch K staging (50.2 KB -> 3 blocks/CU), q prefetch before staging,
// stat-read prefetch before softmax, LDS-staged coalesced epilogue.
__global__ __launch_bounds__(448) void k2_attn(
    unsigned short* __restrict__ qF, const unsigned short* __restrict__ qL,
    const unsigned short* __restrict__ kF, const unsigned short* __restrict__ kL,
    const unsigned short* __restrict__ rgbb, const unsigned short* __restrict__ freb,
    const float* __restrict__ fad_gamma, const float* __restrict__ lfs_gamma,
    float* __restrict__ stats)
{
  const int bc = blockIdx.x, c = bc & 63;
  const size_t plane = (size_t)bc * PP;
  __shared__ __align__(16) unsigned short ksF[PP + 16];   // linear [row*112 + p], +tail pad
  __shared__ __align__(16) unsigned short ksL[PP + 16];
  const int tid = threadIdx.x, lane = tid & 63, w = tid >> 6;
  const int l4 = lane >> 4, lc = lane & 15;

  // ---- q-fragment prefetch (before staging: latency hides under the copy) ----
  const unsigned short* qFp = qF + plane;
  const unsigned short* qLp = qL + plane;
  const int qrow = w*16 + lc;
  short8v aF[4], aL[4];
  #pragma unroll
  for (int ks = 0; ks < 4; ++ks){
    const int joff = ks*32 + l4*8;
    if ((ks < 3) || (l4 < 2)){
      aF[ks] = *(const short8v*)(qFp + qrow*SS + joff);
      aL[ks] = *(const short8v*)(qLp + qrow*SS + joff);
    } else {
      aF[ks] = (short8v)(short)0;
      aL[ks] = (short8v)(short)0;
    }
  }

  // ---- stage K planes: pure linear copy, coalesced, conflict-free ----
  const uint32_t* kFu = (const uint32_t*)kF + plane/2;
  const uint32_t* kLu = (const uint32_t*)kL + plane/2;
  uint32_t* ksFw = (uint32_t*)ksF;
  uint32_t* ksLw = (uint32_t*)ksL;
  #pragma unroll
  for (int t = 0; t < 14; ++t){
    const int i = tid + t*448;
    ksFw[i] = kFu[i];
    ksLw[i] = kLu[i];
  }
  __syncthreads();

  // ---- MFMA: logits tile rows qrow, cols ct*16.. ----
  float4v acc[7];
  #pragma unroll
  for (int ct = 0; ct < 7; ++ct) acc[ct] = (float4v)0.f;
  #pragma unroll
  for (int ks = 0; ks < 4; ++ks){
    #pragma unroll
    for (int ct = 0; ct < 7; ++ct){
      const uint32_t off = (uint32_t)((ct*16 + lc)*224 + ks*64 + l4*16);
      short8v bF = *(const short8v*)((const char*)ksF + off);
      short8v bL = *(const short8v*)((const char*)ksL + off);
      acc[ct] = __builtin_amdgcn_mfma_f32_16x16x32_bf16(aF[ks], bF, acc[ct], 0, 0, 0);
      acc[ct] = __builtin_amdgcn_mfma_f32_16x16x32_bf16(aL[ks], bL, acc[ct], 0, 0, 0);
    }
  }

  // ---- prefetch stat reads (consumed after softmax) ----
  ushort4 frv[7], rgv[7];
  #pragma unroll
  for (int t = 0; t < 7; ++t){
    const int i4 = tid + t*448;
    frv[t] = *(const ushort4*)(freb + plane + (size_t)i4*4);
    rgv[t] = *(const ushort4*)(rgbb + plane + (size_t)i4*4);
  }

  const float sF = 2.f/(1.f + __expf(-fad_gamma[0])) - 1.f;
  const float sL = 2.f/(1.f + __expf(-lfs_gamma[0])) - 1.f;
  unsigned short* attnP = qF + plane;
  unsigned short* alin = ksF;          // dead after MFMA: reuse as attn staging

  __syncthreads();   // all waves done reading ksF/ksL
  #pragma unroll
  for (int r = 0; r < 4; ++r){
    const int i = w*16 + l4*4 + r;
    float v[7];
    #pragma unroll
    for (int ct = 0; ct < 7; ++ct) v[ct] = acc[ct][r];
    float m = fmaxf(fmaxf(fmaxf(v[0],v[1]),fmaxf(v[2],v[3])), fmaxf(fmaxf(v[4],v[5]),v[6]));
    #pragma unroll
    for (int off = 8; off; off >>= 1) m = fmaxf(m, __shfl_xor(m, off, 64));
    float e[7]; float s = 0.f;
    #pragma unroll
    for (int ct = 0; ct < 7; ++ct){ e[ct] = __expf(v[ct] - m); s += e[ct]; }
    #pragma unroll
    for (int off = 8; off; off >>= 1) s += __shfl_xor(s, off, 64);
    const float inv = 1.f / s;
    #pragma unroll
    for (int ct = 0; ct < 7; ++ct)
      alin[i*SS + ct*16 + lc] = f2bf(e[ct] * inv);
  }
  __syncthreads();

  // ---- coalesced pass: attn write (512B/instr) + stats from prefetched regs ----
  float ls1 = 0.f, lq1 = 0.f, ls2 = 0.f, lq2 = 0.f;
  #pragma unroll
  for (int t = 0; t < 7; ++t){
    const int i4 = tid + t*448;
    ushort4 av = *(const ushort4*)(alin + i4*4);
    *(ushort4*)(attnP + (size_t)i4*4) = av;
    const unsigned short* ap = &av.x;
    const unsigned short* fp = &frv[t].x;
    const unsigned short* rp = &rgv[t].x;
    #pragma unroll
    for (int j = 0; j < 4; ++j){
      float a = bf2f(ap[j]);
      float v1 = bf2f(fp[j]) * a * sL;
      float v2 = bf2f(rp[j]) * a * sF;
      ls1 += v1; lq1 += v1*v1; ls2 += v2; lq2 += v2*v2;
    }
  }
  #pragma unroll
  for (int off = 32; off; off >>= 1){
    ls1 += __shfl_xor(ls1, off, 64);
    lq1 += __shfl_xor(lq1, off, 64);
    ls2 += __shfl_xor(ls2, off, 64);
    lq2 += __shfl_xor(lq2, off, 64);
  }
  if (lane == 0){
    atomicAdd(&stats[c],       ls1);
    atomicAdd(&stats[64 + c],  lq1);
    atomicAdd(&stats[128 + c], ls2);
    atomicAdd(&stats[192 + c], lq2);
  }
}

// ---------------- K3: bn1 stats -> affine ----------------
__global__ void k3_affine1(const float* __restrict__ stats,
    const float* __restrict__ fad_cw, const float* __restrict__ fad_bg, const float* __restrict__ fad_bb,
    const float* __restrict__ lfs_cw, const float* __restrict__ lfs_bg, const float* __restrict__ lfs_bb,
    float* __restrict__ AB)
{
  int c = threadIdx.x;
  if (c >= 64) return;
  const float n = 401408.f;
  {
    float m1 = stats[c]/n, v1 = stats[64+c]/n - (stats[c]/n)*(stats[c]/n);
    float cw = fad_cw[c], g = fad_bg[c];
    float rs = rsqrtf(cw*cw*v1 + EPSV);
    AB[c]      = cw*rs*g;
    AB[64 + c] = -cw*m1*rs*g + fad_bb[c];
  }
  {
    float m2 = stats[128+c]/n, v2 = stats[192+c]/n - (stats[128+c]/n)*(stats[128+c]/n);
    float cw = lfs_cw[c], g = lfs_bg[c];
    float rs = rsqrtf(cw*cw*v2 + EPSV);
    AB[128 + c] = cw*rs*g;
    AB[192 + c] = -cw*m2*rs*g + lfs_bb[c];
  }
}

// ---------------- K4: fused y (bf16 out) + pooling + per-plane stats ----------------
__global__ __launch_bounds__(512) void k4_fuse(
    const unsigned short* __restrict__ attn,
    const unsigned short* __restrict__ rgbb, const unsigned short* __restrict__ freb,
    const float* __restrict__ AB1,
    const float* __restrict__ fad_gamma, const float* __restrict__ lfs_gamma,
    unsigned short* __restrict__ ybf, unsigned short* __restrict__ ybl,
    float* __restrict__ avgstat, float* __restrict__ maxstat,
    float4* __restrict__ planeStats)
{
  const int bc = blockIdx.x, b = bc >> 6, c = bc & 63;
  const size_t plane = (size_t)bc * PP;
  __shared__ unsigned short ys[2][112][113];
  __shared__ float redA[8][4];
  __shared__ float redS[8], redM[8];
  const int tid = threadIdx.x, lane = tid & 63, w = tid >> 6;
  const float sF = 2.f/(1.f + __expf(-fad_gamma[0])) - 1.f;
  const float sL = 2.f/(1.f + __expf(-lfs_gamma[0])) - 1.f;
  const float A1 = AB1[c], B1 = AB1[64+c], A2 = AB1[128+c], B2 = AB1[192+c];
  float s0 = 0.f, q0 = 0.f, s1 = 0.f, q1 = 0.f;

  for (int i4 = tid; i4 < 3136; i4 += 512){
    ushort4 av = *(const ushort4*)(attn + plane + (size_t)i4*4);
    ushort4 rg = *(const ushort4*)(rgbb + plane + (size_t)i4*4);
    ushort4 fr = *(const ushort4*)(freb + plane + (size_t)i4*4);
    float aa[4] = {bf2f(av.x), bf2f(av.y), bf2f(av.z), bf2f(av.w)};
    float rr[4] = {bf2f(rg.x), bf2f(rg.y), bf2f(rg.z), bf2f(rg.w)};
    float ff[4] = {bf2f(fr.x), bf2f(fr.y), bf2f(fr.z), bf2f(fr.w)};
    float y0[4], y1[4];
    ushort4 o0, o1;
    unsigned short* p0 = &o0.x; unsigned short* p1 = &o1.x;
    #pragma unroll
    for (int j = 0; j < 4; ++j){
      float t1 = ff[j]*aa[j]*sL;
      float t2 = rr[j]*aa[j]*sF;
      y0[j] = rr[j] + A1*t1 + B1;
      y1[j] = ff[j] + A2*t2 + B2;
      s0 += y0[j]; q0 += y0[j]*y0[j];
      s1 += y1[j]; q1 += y1[j]*y1[j];
      p0[j] = f2bf(y0[j]);
      p1[j] = f2bf(y1[j]);
    }
    *(ushort4*)(ybf + plane + (size_t)i4*4) = o0;
    *(ushort4*)(ybl + plane + (size_t)i4*4) = o1;
    int r = i4 / 28, c0 = (i4 % 28) * 4;
    #pragma unroll
    for (int j = 0; j < 4; ++j){
      ys[0][r][c0+j] = p0[j];
      ys[1][r][c0+j] = p1[j];
    }
  }
  #pragma unroll
  for (int off = 32; off; off >>= 1){
    s0 += __shfl_xor(s0, off, 64); q0 += __shfl_xor(q0, off, 64);
    s1 += __shfl_xor(s1, off, 64); q1 += __shfl_xor(q1, off, 64);
  }
  if (lane == 0){ redA[w][0] = s0; redA[w][1] = q0; redA[w][2] = s1; redA[w][3] = q1; }
  __syncthreads();
  if (tid == 0){
    float a0=0,a1=0,a2=0,a3=0;
    for (int i = 0; i < 8; ++i){ a0+=redA[i][0]; a1+=redA[i][1]; a2+=redA[i][2]; a3+=redA[i][3]; }
    float4 ps = {a0,a1,a2,a3};
    planeStats[bc] = ps;
  }
  __syncthreads();

  const int kk[3] = {3,5,7};
  const int gg[3] = {37,22,16};
  for (int pl = 0; pl < 2; ++pl){
    const int cc = pl*64 + c;
    for (int ki = 0; ki < 3; ++ki){
      const int k = kk[ki], g = gg[ki];
      float sumAll = 0.f, mx = -3.0e38f;
      for (int win = tid; win < g*g; win += 512){
        int wy = win / g, wx = win % g;
        float s = 0.f;
        for (int dy = 0; dy < k; ++dy)
          for (int dx = 0; dx < k; ++dx)
            s += bf2f(ys[pl][wy*k+dy][wx*k+dx]);
        sumAll += s; mx = fmaxf(mx, s);
      }
      #pragma unroll
      for (int off = 32; off; off >>= 1){
        sumAll += __shfl_xor(sumAll, off, 64);
        mx = fmaxf(mx, __shfl_xor(mx, off, 64));
      }
      if (lane == 0){ redS[w] = sumAll; redM[w] = mx; }
      __syncthreads();
      if (tid == 0){
        float st = 0.f, mt = -3.0e38f;
        for (int i = 0; i < 8; ++i){ st += redS[i]; mt = fmaxf(mt, redM[i]); }
        int idx = (b*128 + cc)*3 + ki;
        avgstat[idx] = st / (float)(k*k*g*g);
        maxstat[idx] = mt / (float)(k*k);
      }
      __syncthreads();
    }
  }
}

// ---------------- K6: channel-attention MLP ----------------
__global__ void k6_mlp(const float* __restrict__ avgstat, const float* __restrict__ maxstat,
    const float* __restrict__ lin1, const float* __restrict__ lin2,
    const float* __restrict__ w1, const float* __restrict__ w2,
    float* __restrict__ ca)
{
  const int b = blockIdx.x, tid = threadIdx.x; // 128 threads
  __shared__ float sa[128], sm[128], hA[16], hM[16];
  int idx = (b*128 + tid)*3;
  sa[tid] = avgstat[idx]*lin1[0] + avgstat[idx+1]*lin1[1] + avgstat[idx+2]*lin1[2];
  sm[tid] = maxstat[idx]*lin2[0] + maxstat[idx+1]*lin2[1] + maxstat[idx+2]*lin2[2];
  __syncthreads();
  if (tid < 16){
    float ha = 0.f, hm = 0.f;
    for (int c2 = 0; c2 < 128; ++c2){
      ha += w1[tid*128 + c2]*sa[c2];
      hm += w1[tid*128 + c2]*sm[c2];
    }
    hA[tid] = fmaxf(ha, 0.f); hM[tid] = fmaxf(hm, 0.f);
  }
  __syncthreads();
  float o = 0.f;
  for (int r = 0; r < 16; ++r) o += w2[tid*16 + r]*(hA[r] + hM[r]);
  ca[b*128 + tid] = 1.f/(1.f + __expf(-o));
}

// ---------------- K8: final bn affine from per-plane stats + ca ----------------
__global__ void k8_affineF(const float4* __restrict__ planeStats, const float* __restrict__ ca,
    const float* __restrict__ rgb_cw, const float* __restrict__ rgb_bg, const float* __restrict__ rgb_bb,
    const float* __restrict__ fre_cw, const float* __restrict__ fre_bg, const float* __restrict__ fre_bb,
    float* __restrict__ ABF)
{
  int t = threadIdx.x;
  if (t >= 128) return;
  int z = t >> 6, c = t & 63;
  float S = 0.f, Q = 0.f;
  for (int b = 0; b < 32; ++b){
    float4 ps = planeStats[b*64 + c];
    float sc = ca[b*128 + t];
    float sp = z ? ps.z : ps.x;
    float qp = z ? ps.w : ps.y;
    S += sc*sp; Q += sc*sc*qp;
  }
  const float n = 401408.f;
  float m = S/n, v = Q/n - m*m;
  float cw = z ? fre_cw[c] : rgb_cw[c];
  float g  = z ? fre_bg[c] : rgb_bg[c];
  float bb = z ? fre_bb[c] : rgb_bb[c];
  float rs = rsqrtf(cw*cw*v + EPSV);
  ABF[z*128 + c]      = cw*rs*g;
  ABF[z*128 + 64 + c] = -cw*m*rs*g + bb;
}

// ---------------- K9: out = y*(1 + A*ca) + B (bf16 y in, fp32 out) ----------------
__global__ __launch_bounds__(256) void k9_out(
    const unsigned short* __restrict__ ybf, const unsigned short* __restrict__ ybl,
    const float* __restrict__ ca, const float* __restrict__ ABF,
    float* __restrict__ out)
{
  const int c = blockIdx.x, b = blockIdx.y, z = blockIdx.z;
  const size_t plane = ((size_t)b*64 + c)*PP;
  const unsigned short* y = z ? ybl : ybf;
  float* o = out + (z ? NE : 0) + plane;
  const float sc = ca[b*128 + z*64 + c];
  const float A = ABF[z*128 + c], Bv = ABF[z*128 + 64 + c];
  const float mul = 1.f + A*sc;
  for (int i8 = threadIdx.x; i8 < 1568; i8 += 256){
    short8v yv = *(const short8v*)(y + plane + (size_t)i8*8);
    float4 o0, o1;
    o0.x = bf2f((unsigned short)yv[0])*mul + Bv;
    o0.y = bf2f((unsigned short)yv[1])*mul + Bv;
    o0.z = bf2f((unsigned short)yv[2])*mul + Bv;
    o0.w = bf2f((unsigned short)yv[3])*mul + Bv;
    o1.x = bf2f((unsigned short)yv[4])*mul + Bv;
    o1.y = bf2f((unsigned short)yv[5])*mul + Bv;
    o1.z = bf2f((unsigned short)yv[6])*mul + Bv;
    o1.w = bf2f((unsigned short)yv[7])*mul + Bv;
    *(float4*)(&o[(size_t)i8*8])     = o0;
    *(float4*)(&o[(size_t)i8*8 + 4]) = o1;
  }
}

extern "C" void kernel_launch(void* const* d_in, const int* in_sizes, int n_in,
                              void* d_out, int out_size, void* d_ws, size_t ws_size,
                              hipStream_t stream)
{
  (void)in_sizes; (void)n_in; (void)out_size; (void)ws_size;
  const float* rgb      = (const float*)d_in[0];
  const float* fre      = (const float*)d_in[1];
  const float* wq_fad   = (const float*)d_in[2];
  const float* bq_fad   = (const float*)d_in[3];
  const float* wq_lfs   = (const float*)d_in[4];
  const float* bq_lfs   = (const float*)d_in[5];
  const float* wk_fad   = (const float*)d_in[6];
  const float* bk_fad   = (const float*)d_in[7];
  const float* wk_lfs   = (const float*)d_in[8];
  const float* bk_lfs   = (const float*)d_in[9];
  const float* fad_gamma= (const float*)d_in[10];
  const float* lfs_gamma= (const float*)d_in[11];
  const float* fad_cw   = (const float*)d_in[12];
  const float* fad_bg   = (const float*)d_in[14];
  const float* fad_bb   = (const float*)d_in[15];
  const float* lfs_cw   = (const float*)d_in[16];
  const float* lfs_bg   = (const float*)d_in[18];
  const float* lfs_bb   = (const float*)d_in[19];
  const float* lin1_w   = (const float*)d_in[20];
  const float* lin2_w   = (const float*)d_in[21];
  const float* mlp_w1   = (const float*)d_in[22];
  const float* mlp_w2   = (const float*)d_in[23];
  const float* rgb_cw   = (const float*)d_in[24];
  const float* rgb_bg   = (const float*)d_in[26];
  const float* rgb_bb   = (const float*)d_in[27];
  const float* fre_cw   = (const float*)d_in[28];
  const float* fre_bg   = (const float*)d_in[30];
  const float* fre_bb   = (const float*)d_in[31];

  char* ws = (char*)d_ws;
  unsigned short* qF = (unsigned short*)(ws);          // becomes attn after k2
  unsigned short* qL = (unsigned short*)(ws + 2*NE);
  unsigned short* kF = (unsigned short*)(ws + 4*NE);   // becomes y_fad (bf16) after k4
  unsigned short* kL = (unsigned short*)(ws + 6*NE);   // becomes y_lfs (bf16) after k4
  float* sbase = (float*)(ws + 8*NE);
  float* stats      = sbase;               // [0..255]   bn1 atomics (memset)
  float* AB1        = sbase + 256;
  float* avgstat    = sbase + 512;
  float* maxstat    = sbase + 12800;
  float* ca         = sbase + 25088;
  float* ABF        = sbase + 29184;
  float4* planeStats= (float4*)(sbase + 29440);
  unsigned short* rgbb = (unsigned short*)d_out;
  unsigned short* freb = (unsigned short*)d_out + NE;

  hipMemsetAsync(stats, 0, 256*sizeof(float), stream);

  k1_conv<<<dim3(49,32,2), dim3(256), 0, stream>>>(rgb, fre,
      wq_fad, bq_fad, wk_fad, bk_fad, wq_lfs, bq_lfs, wk_lfs, bk_lfs,
      qF, kF, qL, kL, rgbb, freb);
  k2_attn<<<dim3(2048), dim3(448), 0, stream>>>(qF, qL, kF, kL,
      rgbb, freb, fad_gamma, lfs_gamma, stats);
  k3_affine1<<<dim3(1), dim3(64), 0, stream>>>(stats,
      fad_cw, fad_bg, fad_bb, lfs_cw, lfs_bg, lfs_bb, AB1);
  k4_fuse<<<dim3(2048), dim3(512), 0, stream>>>((const unsigned short*)qF,
      rgbb, freb, AB1, fad_gamma, lfs_gamma, kF, kL, avgstat, maxstat, planeStats);
  k6_mlp<<<dim3(32), dim3(128), 0, stream>>>(avgstat, maxstat,
      lin1_w, lin2_w, mlp_w1, mlp_w2, ca);
  k8_affineF<<<dim3(1), dim3(128), 0, stream>>>(planeStats, ca,
      rgb_cw, rgb_bg, rgb_bb, fre_cw, fre_bg, fre_bb, ABF);
  k9_out<<<dim3(64,32,2), dim3(256), 0, stream>>>(kF, kL, ca, ABF,
      (float*)d_out);
}